// Round 12
// baseline (1236.490 us; speedup 1.0000x reference)
//
#include <hip/hip_runtime.h>

typedef unsigned short ushort_t;
typedef __bf16 bf16x8 __attribute__((ext_vector_type(8)));
typedef float f32x4 __attribute__((ext_vector_type(4)));

#define SEQ_ 577
#define D_ 384
#define NTOK (16 * 577)   // 9232

enum { M_QKV = 0, M_OUT, M_MLP1, M_MLP2 };

__device__ inline float b2f(ushort_t u) {
    unsigned int x = ((unsigned int)u) << 16;
    float f; __builtin_memcpy(&f, &x, 4); return f;
}
__device__ inline ushort_t f2b(float f) {
    unsigned int x; __builtin_memcpy(&x, &f, 4);
    x = x + 0x7fffu + ((x >> 16) & 1u);
    return (ushort_t)(x >> 16);
}

// ---------------------------------------------------------------------------
// 64x64 tile transpose+convert: src f32 [K,N] (ld ldn) -> dst bf16 [N,K]
// ---------------------------------------------------------------------------
__device__ void transpose_tile(const float* __restrict__ src,
                               ushort_t* __restrict__ dst,
                               int ldn, int ldk, int k0, int n0)
{
    __shared__ float t[64][65];
    const int tid = threadIdx.x;
    const int c = tid & 63, rr = tid >> 6;
#pragma unroll
    for (int i = 0; i < 16; i++) {
        int kl = rr + i * 4;
        t[kl][c] = src[(size_t)(k0 + kl) * ldn + n0 + c];
    }
    __syncthreads();
#pragma unroll
    for (int i = 0; i < 16; i++) {
        int nl = rr + i * 4;
        dst[(size_t)(n0 + nl) * ldk + k0 + c] = f2b(t[c][nl]);
    }
}

// All 6 layers' weights + SPT weight in ONE dispatch: 6*432 + 360 = 2952 blocks.
__global__ __launch_bounds__(256) void prep_all_kernel(
    const float* __restrict__ wqkv, const float* __restrict__ wout,
    const float* __restrict__ w1, const float* __restrict__ w2,
    const float* __restrict__ spt_w,
    ushort_t* __restrict__ W6, ushort_t* __restrict__ spt_wt)
{
    int id = blockIdx.x;
    if (id >= 2592) {
        int r2 = id - 2592;                 // 360 blocks: 60 ktiles x 6 ntiles
        int kt = r2 % 60, nt = r2 / 60;
        transpose_tile(spt_w, spt_wt, 384, 3840, kt * 64, nt * 64);
        return;
    }
    int l = id / 432;
    int r = id - l * 432;
    ushort_t* qkv_t  = W6 + (size_t)l * 1769472;
    ushort_t* wout_t = qkv_t + 442368;
    ushort_t* w1_t   = wout_t + 147456;
    ushort_t* w2_t   = w1_t + 589824;
    const float* wq = wqkv + (size_t)l * 442368;
    const float* wo = wout + (size_t)l * 147456;
    const float* W1 = w1 + (size_t)l * 589824;
    const float* W2 = w2 + (size_t)l * 589824;
    if (r < 108) {
        int kt = r / 18, nt = r % 18;
        transpose_tile(wq, qkv_t, 1152, 384, kt * 64, nt * 64);
    } else if (r < 144) {
        r -= 108; int kt = r / 6, nt = r % 6;
        transpose_tile(wo, wout_t, 384, 384, kt * 64, nt * 64);
    } else if (r < 288) {
        r -= 144; int kt = r / 24, nt = r % 24;
        transpose_tile(W1, w1_t, 1536, 384, kt * 64, nt * 64);
    } else {
        r -= 288; int kt = r / 6, nt = r % 6;
        transpose_tile(W2, w2_t, 384, 1536, kt * 64, nt * 64);
    }
}

// ---------------------------------------------------------------------------
// 128x64-tile distance-2 pipelined GEMM for wide-N ops (QKV).
// 256 threads = 4 waves, each wave 64x32 (4x2 of 16x16x32 bf16).
// Compile-time NK: K-loop fully unrolled. Bijective chunked XCD swizzle.
// M-tail loads unguarded (A in workspace), stores guarded.
// ---------------------------------------------------------------------------
template <int MODE, int NK>
__global__ __launch_bounds__(256) void gemm12864(
    const ushort_t* __restrict__ A, const ushort_t* __restrict__ Bt,
    ushort_t* __restrict__ Co, const float* __restrict__ bias,
    int M, int ldc)
{
    const int K = NK * 32;
    __shared__ __align__(16) ushort_t As[2][128][40];
    __shared__ __align__(16) ushort_t Bs[2][64][40];

    const int gx = gridDim.x;
    const int nwg = gx * gridDim.y;
    const int f = blockIdx.y * gx + blockIdx.x;
    const int q = nwg >> 3, rr_ = nwg & 7;
    const int xcd = f & 7, ii = f >> 3;
    const int swz = (xcd < rr_ ? xcd * (q + 1) : rr_ * (q + 1) + (xcd - rr_) * q) + ii;
    const int bx = swz % gx, by = swz / gx;

    const int tid = threadIdx.x;
    const int rowBase = by * 128;
    const int colBase = bx * 64;
    const int lr = tid >> 2, lk = (tid & 3) * 8;
    const int wv = tid >> 6, lane = tid & 63;
    const int wm = (wv >> 1) * 64, wn = (wv & 1) * 32;
    const int m16 = lane & 15, q4 = lane >> 4, kb = q4 * 8;

    const ushort_t* pa0 = A + (size_t)(rowBase + lr) * K + lk;
    const ushort_t* pa1 = pa0 + (size_t)64 * K;
    const ushort_t* pb  = Bt + (size_t)(colBase + lr) * K + lk;

    f32x4 acc[4][2];
#pragma unroll
    for (int i = 0; i < 4; i++)
#pragma unroll
        for (int j = 0; j < 2; j++) acc[i][j] = (f32x4){0.f, 0.f, 0.f, 0.f};

    uint4 Ua0, Ua1, Ub, Va0, Va1, Vb;
    auto gloadU = [&](int kt) {
        Ua0 = *(const uint4*)(pa0 + kt * 32);
        Ua1 = *(const uint4*)(pa1 + kt * 32);
        Ub  = *(const uint4*)(pb + kt * 32);
    };
    auto gloadV = [&](int kt) {
        Va0 = *(const uint4*)(pa0 + kt * 32);
        Va1 = *(const uint4*)(pa1 + kt * 32);
        Vb  = *(const uint4*)(pb + kt * 32);
    };
    auto swriteU = [&](int buf) {
        *(uint4*)&As[buf][lr][lk] = Ua0;
        *(uint4*)&As[buf][64 + lr][lk] = Ua1;
        *(uint4*)&Bs[buf][lr][lk] = Ub;
    };
    auto swriteV = [&](int buf) {
        *(uint4*)&As[buf][lr][lk] = Va0;
        *(uint4*)&As[buf][64 + lr][lk] = Va1;
        *(uint4*)&Bs[buf][lr][lk] = Vb;
    };
    auto compute = [&](int buf) {
        bf16x8 af[4];
#pragma unroll
        for (int mt = 0; mt < 4; mt++)
            af[mt] = *(const bf16x8*)&As[buf][wm + mt * 16 + m16][kb];
        bf16x8 b0 = *(const bf16x8*)&Bs[buf][wn + m16][kb];
        bf16x8 b1 = *(const bf16x8*)&Bs[buf][wn + 16 + m16][kb];
#pragma unroll
        for (int mt = 0; mt < 4; mt++) {
            acc[mt][0] = __builtin_amdgcn_mfma_f32_16x16x32_bf16(af[mt], b0, acc[mt][0], 0, 0, 0);
            acc[mt][1] = __builtin_amdgcn_mfma_f32_16x16x32_bf16(af[mt], b1, acc[mt][1], 0, 0, 0);
        }
    };

    gloadU(0);
    swriteU(0);
    gloadU(1);
    gloadV(2);
    __syncthreads();

#pragma unroll
    for (int kt = 0; kt < NK; kt += 2) {
        swriteU(1);
        if (kt + 3 < NK) gloadU(kt + 3);
        compute(0);
        __syncthreads();
        if (kt + 2 < NK) {
            swriteV(0);
            if (kt + 4 < NK) gloadV(kt + 4);
        }
        compute(1);
        __syncthreads();
    }

#pragma unroll
    for (int mt = 0; mt < 4; mt++)
#pragma unroll
        for (int nt = 0; nt < 2; nt++) {
            int col = colBase + wn + nt * 16 + m16;
#pragma unroll
            for (int r = 0; r < 4; r++) {
                int row = rowBase + wm + mt * 16 + q4 * 4 + r;
                if (row >= M) continue;
                float v = acc[mt][nt][r];
                if (MODE == M_QKV) {
                    Co[(size_t)row * ldc + col] = f2b(v);
                } else if (MODE == M_MLP1) {
                    float t = v + bias[col];
                    float u = t * (0.7978845608f + 0.0356774081f * t * t);
                    float e = __builtin_amdgcn_exp2f(2.885390082f * u);
                    float gl = t - t * __builtin_amdgcn_rcpf(e + 1.0f);
                    Co[(size_t)row * ldc + col] = f2b(gl);
                }
            }
        }
}

// ---------------------------------------------------------------------------
// LN-fused 128x64 GEMM for MLP1: A = x (f32 residual), per-row mean/rstd
// from the stats table produced by the OUT epilogue (12 slots/row of
// (sum,sumsq) 32-col partials -> summed here once per row). Staging
// normalizes f32 -> LN -> gamma/beta -> bf16. Replaces the standalone
// ff-LN dispatch (round-3 lesson: fusion is only viable with stats
// precomputed once per row, not recomputed per column-tile).
// ---------------------------------------------------------------------------
template <int NK>
__global__ __launch_bounds__(256) void gemm12864_ln(
    const float* __restrict__ X, const ushort_t* __restrict__ Bt,
    ushort_t* __restrict__ Co, const float* __restrict__ bias,
    const float* __restrict__ stats, const float* __restrict__ lng,
    const float* __restrict__ lnb, int M, int ldc)
{
    const int K = NK * 32;   // 384
    __shared__ __align__(16) ushort_t As[2][128][40];
    __shared__ __align__(16) ushort_t Bs[2][64][40];

    const int gx = gridDim.x;
    const int nwg = gx * gridDim.y;
    const int f = blockIdx.y * gx + blockIdx.x;
    const int q = nwg >> 3, rr_ = nwg & 7;
    const int xcd = f & 7, ii = f >> 3;
    const int swz = (xcd < rr_ ? xcd * (q + 1) : rr_ * (q + 1) + (xcd - rr_) * q) + ii;
    const int bx = swz % gx, by = swz / gx;

    const int tid = threadIdx.x;
    const int rowBase = by * 128;
    const int colBase = bx * 64;
    const int lr = tid >> 2, lk = (tid & 3) * 8;
    const int wv = tid >> 6, lane = tid & 63;
    const int wm = (wv >> 1) * 64, wn = (wv & 1) * 32;
    const int m16 = lane & 15, q4 = lane >> 4, kb = q4 * 8;

    int ar0 = rowBase + lr;       if (ar0 >= M) ar0 = M - 1;
    int ar1 = rowBase + 64 + lr;  if (ar1 >= M) ar1 = M - 1;

    float rstd0, nc0, rstd1, nc1;
    {
        const float4* sp = (const float4*)(stats + (size_t)ar0 * 24);
        float s = 0.f, sq = 0.f;
#pragma unroll
        for (int i = 0; i < 6; i++) { float4 v = sp[i]; s += v.x + v.z; sq += v.y + v.w; }
        float mean = s * (1.f / 384.f);
        rstd0 = rsqrtf(sq * (1.f / 384.f) - mean * mean + 1e-5f);
        nc0 = -mean * rstd0;
    }
    {
        const float4* sp = (const float4*)(stats + (size_t)ar1 * 24);
        float s = 0.f, sq = 0.f;
#pragma unroll
        for (int i = 0; i < 6; i++) { float4 v = sp[i]; s += v.x + v.z; sq += v.y + v.w; }
        float mean = s * (1.f / 384.f);
        rstd1 = rsqrtf(sq * (1.f / 384.f) - mean * mean + 1e-5f);
        nc1 = -mean * rstd1;
    }

    const float* px0 = X + (size_t)ar0 * K + lk;
    const float* px1 = X + (size_t)ar1 * K + lk;
    const ushort_t* pb = Bt + (size_t)(colBase + lr) * K + lk;

    f32x4 acc[4][2];
#pragma unroll
    for (int i = 0; i < 4; i++)
#pragma unroll
        for (int j = 0; j < 2; j++) acc[i][j] = (f32x4){0.f, 0.f, 0.f, 0.f};

    float4 U0a, U0b, U1a, U1b, V0a, V0b, V1a, V1b;
    uint4 Ub, Vb;
    auto gloadU = [&](int kt) {
        const float4* p0 = (const float4*)(px0 + kt * 32);
        U0a = p0[0]; U0b = p0[1];
        const float4* p1 = (const float4*)(px1 + kt * 32);
        U1a = p1[0]; U1b = p1[1];
        Ub = *(const uint4*)(pb + kt * 32);
    };
    auto gloadV = [&](int kt) {
        const float4* p0 = (const float4*)(px0 + kt * 32);
        V0a = p0[0]; V0b = p0[1];
        const float4* p1 = (const float4*)(px1 + kt * 32);
        V1a = p1[0]; V1b = p1[1];
        Vb = *(const uint4*)(pb + kt * 32);
    };
    // normalize 8 f32 with LN affine for K-columns kt*32+lk..+7
    auto nrm8 = [&](float4 a, float4 b2, float rstd, float nc, int ktd) -> bf16x8 {
        const float4 g0 = *(const float4*)(lng + ktd * 32 + lk);
        const float4 g1 = *(const float4*)(lng + ktd * 32 + lk + 4);
        const float4 bb0 = *(const float4*)(lnb + ktd * 32 + lk);
        const float4 bb1 = *(const float4*)(lnb + ktd * 32 + lk + 4);
        bf16x8 r;
        r[0] = (__bf16)(fmaf(a.x, rstd, nc) * g0.x + bb0.x);
        r[1] = (__bf16)(fmaf(a.y, rstd, nc) * g0.y + bb0.y);
        r[2] = (__bf16)(fmaf(a.z, rstd, nc) * g0.z + bb0.z);
        r[3] = (__bf16)(fmaf(a.w, rstd, nc) * g0.w + bb0.w);
        r[4] = (__bf16)(fmaf(b2.x, rstd, nc) * g1.x + bb1.x);
        r[5] = (__bf16)(fmaf(b2.y, rstd, nc) * g1.y + bb1.y);
        r[6] = (__bf16)(fmaf(b2.z, rstd, nc) * g1.z + bb1.z);
        r[7] = (__bf16)(fmaf(b2.w, rstd, nc) * g1.w + bb1.w);
        return r;
    };
    auto swriteU = [&](int buf, int ktd) {
        *(bf16x8*)&As[buf][lr][lk] = nrm8(U0a, U0b, rstd0, nc0, ktd);
        *(bf16x8*)&As[buf][64 + lr][lk] = nrm8(U1a, U1b, rstd1, nc1, ktd);
        *(uint4*)&Bs[buf][lr][lk] = Ub;
    };
    auto swriteV = [&](int buf, int ktd) {
        *(bf16x8*)&As[buf][lr][lk] = nrm8(V0a, V0b, rstd0, nc0, ktd);
        *(bf16x8*)&As[buf][64 + lr][lk] = nrm8(V1a, V1b, rstd1, nc1, ktd);
        *(uint4*)&Bs[buf][lr][lk] = Vb;
    };
    auto compute = [&](int buf) {
        bf16x8 af[4];
#pragma unroll
        for (int mt = 0; mt < 4; mt++)
            af[mt] = *(const bf16x8*)&As[buf][wm + mt * 16 + m16][kb];
        bf16x8 b0 = *(const bf16x8*)&Bs[buf][wn + m16][kb];
        bf16x8 b1 = *(const bf16x8*)&Bs[buf][wn + 16 + m16][kb];
#pragma unroll
        for (int mt = 0; mt < 4; mt++) {
            acc[mt][0] = __builtin_amdgcn_mfma_f32_16x16x32_bf16(af[mt], b0, acc[mt][0], 0, 0, 0);
            acc[mt][1] = __builtin_amdgcn_mfma_f32_16x16x32_bf16(af[mt], b1, acc[mt][1], 0, 0, 0);
        }
    };

    gloadU(0);
    swriteU(0, 0);
    gloadU(1);
    gloadV(2);
    __syncthreads();

#pragma unroll
    for (int kt = 0; kt < NK; kt += 2) {
        swriteU(1, kt + 1);
        if (kt + 3 < NK) gloadU(kt + 3);
        compute(0);
        __syncthreads();
        if (kt + 2 < NK) {
            swriteV(0, kt + 2);
            if (kt + 4 < NK) gloadV(kt + 4);
        }
        compute(1);
        __syncthreads();
    }

#pragma unroll
    for (int mt = 0; mt < 4; mt++)
#pragma unroll
        for (int nt = 0; nt < 2; nt++) {
            int col = colBase + wn + nt * 16 + m16;
#pragma unroll
            for (int r = 0; r < 4; r++) {
                int row = rowBase + wm + mt * 16 + q4 * 4 + r;
                if (row >= M) continue;
                float t = acc[mt][nt][r] + bias[col];
                float u = t * (0.7978845608f + 0.0356774081f * t * t);
                float e = __builtin_amdgcn_exp2f(2.885390082f * u);
                float gl = t - t * __builtin_amdgcn_rcpf(e + 1.0f);
                Co[(size_t)row * ldc + col] = f2b(gl);
            }
        }
}

// ---------------------------------------------------------------------------
// 64x64-tile distance-2 pipelined GEMM (OUT / MLP2).
// resid f32 += v + bias. M_OUT additionally emits per-row LN stat partials:
// each wave reduces its 32-col slice (shfl over the m16 group) and writes
// (sum,sumsq) to stats[row][slot], slot = bx*2 + (wv&1) in 0..11.
// ---------------------------------------------------------------------------
template <int MODE, int NK>
__global__ __launch_bounds__(256) void gemm64(
    const ushort_t* __restrict__ A, const ushort_t* __restrict__ Bt,
    float* __restrict__ resid, const float* __restrict__ bias,
    float* __restrict__ stats, int M, int ldc)
{
    const int K = NK * 32;
    __shared__ __align__(16) ushort_t As[2][64][40];
    __shared__ __align__(16) ushort_t Bs[2][64][40];

    const int gx = gridDim.x, gy = gridDim.y;
    const int nwg = gx * gy;
    const int f = blockIdx.y * gx + blockIdx.x;
    const int q = nwg >> 3, rr_ = nwg & 7;
    const int xcd = f & 7, ii = f >> 3;
    const int swz = (xcd < rr_ ? xcd * (q + 1) : rr_ * (q + 1) + (xcd - rr_) * q) + ii;
    const int bx = swz % gx, by = swz / gx;

    const int tid = threadIdx.x;
    const int rowBase = by * 64;
    const int colBase = bx * 64;
    const int lr = tid >> 2, lk = (tid & 3) * 8;
    const int wv = tid >> 6, lane = tid & 63;
    const int wm = (wv >> 1) * 32, wn = (wv & 1) * 32;
    const int m16 = lane & 15, q4 = lane >> 4, kb = q4 * 8;

    const ushort_t* pa = A + (size_t)(rowBase + lr) * K + lk;
    const ushort_t* pb = Bt + (size_t)(colBase + lr) * K + lk;

    f32x4 acc[2][2];
#pragma unroll
    for (int i = 0; i < 2; i++)
#pragma unroll
        for (int j = 0; j < 2; j++) acc[i][j] = (f32x4){0.f, 0.f, 0.f, 0.f};

    uint4 Ua, Ub, Va, Vb;
    auto gloadU = [&](int kt) {
        Ua = *(const uint4*)(pa + kt * 32);
        Ub = *(const uint4*)(pb + kt * 32);
    };
    auto gloadV = [&](int kt) {
        Va = *(const uint4*)(pa + kt * 32);
        Vb = *(const uint4*)(pb + kt * 32);
    };
    auto swriteU = [&](int buf) {
        *(uint4*)&As[buf][lr][lk] = Ua;
        *(uint4*)&Bs[buf][lr][lk] = Ub;
    };
    auto swriteV = [&](int buf) {
        *(uint4*)&As[buf][lr][lk] = Va;
        *(uint4*)&Bs[buf][lr][lk] = Vb;
    };
    auto compute = [&](int buf) {
        bf16x8 a0 = *(const bf16x8*)&As[buf][wm + m16][kb];
        bf16x8 a1 = *(const bf16x8*)&As[buf][wm + 16 + m16][kb];
        bf16x8 b0 = *(const bf16x8*)&Bs[buf][wn + m16][kb];
        bf16x8 b1 = *(const bf16x8*)&Bs[buf][wn + 16 + m16][kb];
        acc[0][0] = __builtin_amdgcn_mfma_f32_16x16x32_bf16(a0, b0, acc[0][0], 0, 0, 0);
        acc[0][1] = __builtin_amdgcn_mfma_f32_16x16x32_bf16(a0, b1, acc[0][1], 0, 0, 0);
        acc[1][0] = __builtin_amdgcn_mfma_f32_16x16x32_bf16(a1, b0, acc[1][0], 0, 0, 0);
        acc[1][1] = __builtin_amdgcn_mfma_f32_16x16x32_bf16(a1, b1, acc[1][1], 0, 0, 0);
    };

    gloadU(0);
    swriteU(0);
    gloadU(1);
    gloadV(2);
    __syncthreads();

#pragma unroll
    for (int kt = 0; kt < NK; kt += 2) {
        swriteU(1);
        if (kt + 3 < NK) gloadU(kt + 3);
        compute(0);
        __syncthreads();
        if (kt + 2 < NK) {
            swriteV(0);
            if (kt + 4 < NK) gloadV(kt + 4);
        }
        compute(1);
        __syncthreads();
    }

#pragma unroll
    for (int im = 0; im < 2; im++)
#pragma unroll
        for (int r = 0; r < 4; r++) {
            int row = rowBase + wm + im * 16 + q4 * 4 + r;
            float s = 0.f, sq = 0.f;
#pragma unroll
            for (int in = 0; in < 2; in++) {
                int col = colBase + wn + in * 16 + m16;
                if (row < M) {
                    size_t o = (size_t)row * ldc + col;
                    float v = resid[o] + acc[im][in][r] + bias[col];
                    resid[o] = v;
                    s += v; sq += v * v;
                }
            }
            if (MODE == M_OUT) {
                s += __shfl_xor(s, 1);  s += __shfl_xor(s, 2);
                s += __shfl_xor(s, 4);  s += __shfl_xor(s, 8);
                sq += __shfl_xor(sq, 1); sq += __shfl_xor(sq, 2);
                sq += __shfl_xor(sq, 4); sq += __shfl_xor(sq, 8);
                if (m16 == 0 && row < M) {
                    int slot = bx * 2 + (wv & 1);
                    stats[(size_t)row * 24 + slot * 2]     = s;
                    stats[(size_t)row * 24 + slot * 2 + 1] = sq;
                }
            }
        }
}

// ---------------------------------------------------------------------------
// Split-K (z=4) depth-2 double-buffered 64x64 GEMM for the SPT embed.
// Grid (6,48,4) = 1152 blocks, nk=30 per split. atomicAdd partials into
// resid (pre-initialized with spt_bias + pos). Chunked XCD swizzle.
// ---------------------------------------------------------------------------
__global__ __launch_bounds__(256) void gemm64_spt_split(
    const ushort_t* __restrict__ A, const ushort_t* __restrict__ Bt,
    float* __restrict__ resid, int rowOff)
{
    __shared__ __align__(16) ushort_t As[2][64][40];
    __shared__ __align__(16) ushort_t Bs[2][64][40];

    const int f = blockIdx.z * 288 + blockIdx.y * 6 + blockIdx.x;
    const int swz = (f & 7) * 144 + (f >> 3);
    const int bz = swz / 288;
    const int rem = swz - bz * 288;
    const int by = rem / 6, bx = rem - by * 6;

    const int K = 3840, nk = 30;
    const int rowBase = by * 64;
    const int colBase = bx * 64;
    const int kbase = bz * 960;

    const int tid = threadIdx.x;
    const int lr = tid >> 2, lk = (tid & 3) * 8;
    const int wv = tid >> 6, lane = tid & 63;
    const int wm = (wv >> 1) * 32, wn = (wv & 1) * 32;
    const int m16 = lane & 15, q4 = lane >> 4, kb = q4 * 8;

    const ushort_t* pa = A + (size_t)(rowBase + lr) * K + kbase + lk;
    const ushort_t* pb = Bt + (size_t)(colBase + lr) * K + kbase + lk;

    f32x4 acc[2][2];
#pragma unroll
    for (int i = 0; i < 2; i++)
#pragma unroll
        for (int j = 0; j < 2; j++) acc[i][j] = (f32x4){0.f, 0.f, 0.f, 0.f};

    uint4 Ua, Ub, Va, Vb;
    auto gloadU = [&](int kt) {
        Ua = *(const uint4*)(pa + kt * 32);
        Ub = *(const uint4*)(pb + kt * 32);
    };
    auto gloadV = [&](int kt) {
        Va = *(const uint4*)(pa + kt * 32);
        Vb = *(const uint4*)(pb + kt * 32);
    };
    auto swriteU = [&](int buf) {
        *(uint4*)&As[buf][lr][lk] = Ua;
        *(uint4*)&Bs[buf][lr][lk] = Ub;
    };
    auto swriteV = [&](int buf) {
        *(uint4*)&As[buf][lr][lk] = Va;
        *(uint4*)&Bs[buf][lr][lk] = Vb;
    };
    auto compute = [&](int buf) {
        bf16x8 a0 = *(const bf16x8*)&As[buf][wm + m16][kb];
        bf16x8 a1 = *(const bf16x8*)&As[buf][wm + 16 + m16][kb];
        bf16x8 b0 = *(const bf16x8*)&Bs[buf][wn + m16][kb];
        bf16x8 b1 = *(const bf16x8*)&Bs[buf][wn + 16 + m16][kb];
        acc[0][0] = __builtin_amdgcn_mfma_f32_16x16x32_bf16(a0, b0, acc[0][0], 0, 0, 0);
        acc[0][1] = __builtin_amdgcn_mfma_f32_16x16x32_bf16(a0, b1, acc[0][1], 0, 0, 0);
        acc[1][0] = __builtin_amdgcn_mfma_f32_16x16x32_bf16(a1, b0, acc[1][0], 0, 0, 0);
        acc[1][1] = __builtin_amdgcn_mfma_f32_16x16x32_bf16(a1, b1, acc[1][1], 0, 0, 0);
    };

    gloadU(0);
    swriteU(0);
    gloadU(1);
    gloadV(2);
    __syncthreads();

    for (int kt = 0; kt < nk; kt += 2) {
        swriteU(1);
        if (kt + 3 < nk) gloadU(kt + 3);
        compute(0);
        __syncthreads();
        if (kt + 2 < nk) {
            swriteV(0);
            if (kt + 4 < nk) gloadV(kt + 4);
        }
        compute(1);
        __syncthreads();
    }

#pragma unroll
    for (int im = 0; im < 2; im++)
#pragma unroll
        for (int in = 0; in < 2; in++) {
            int col = colBase + wn + in * 16 + m16;
#pragma unroll
            for (int r = 0; r < 4; r++) {
                int row = rowBase + wm + im * 16 + q4 * 4 + r;
                int grow = rowOff + row;
                int bb = grow / 576, p = grow - bb * 576;
                size_t o = ((size_t)(bb * SEQ_ + 1 + p)) * D_ + col;
                atomicAdd(&resid[o], acc[im][in][r]);
            }
        }
}

// ---------------------------------------------------------------------------
// Fused flash attention (one layer). Grid (10 qtiles, 96 b*h), 256 thr.
// Chunked XCD swizzle + one-iteration load-ahead + setprio on MFMA clusters.
// ---------------------------------------------------------------------------
__global__ __launch_bounds__(256) void attn_kernel(
    const ushort_t* __restrict__ qkv, ushort_t* __restrict__ attn,
    const float* __restrict__ temp, int layer)
{
    const int f = blockIdx.y * 10 + blockIdx.x;          // 960 blocks, 960%8==0
    const int swz = (f & 7) * 120 + (f >> 3);            // chunked XCD swizzle
    const int qt = swz % 10;
    const int bh = swz / 10;
    const int b = bh / 6, hd = bh - b * 6;
    const int tid = threadIdx.x;
    const int wv = tid >> 6, lane = tid & 63;
    const int m16 = lane & 15, q4 = lane >> 4;
    const float sc2 = expf(temp[layer]) * 1.44269504f;

    __shared__ __align__(16) ushort_t Ks[64][72];
    __shared__ __align__(16) ushort_t Vt[64][72];
    __shared__ __align__(16) ushort_t Pw[4][16][72];

    const int qrow = qt * 64 + wv * 16 + m16;
    const int qtok = qrow < SEQ_ ? qrow : SEQ_ - 1;
    const ushort_t* qb = qkv + ((size_t)(b * SEQ_ + qtok)) * 1152 + hd * 64;
    bf16x8 qf0 = *(const bf16x8*)(qb + q4 * 8);
    bf16x8 qf1 = *(const bf16x8*)(qb + 32 + q4 * 8);

    f32x4 accO[4];
#pragma unroll
    for (int dt = 0; dt < 4; dt++) accO[dt] = (f32x4){0.f, 0.f, 0.f, 0.f};
    float l_r[4] = {0.f, 0.f, 0.f, 0.f};

    const int skey = tid >> 2;
    const int scol = (tid & 3) * 16;
    const int vp   = tid & 31;
    const int vdh  = (tid >> 5) * 8;

    uint4 kv0, kv1, va, vb2;
    auto loadKV = [&](int kt) {
        int key = kt * 64 + skey;
        int gkey = key < SEQ_ ? key : 0;
        const ushort_t* kb_ = qkv + ((size_t)(b * SEQ_ + gkey)) * 1152 + 384 + hd * 64;
        kv0 = *(const uint4*)(kb_ + scol);
        kv1 = *(const uint4*)(kb_ + scol + 8);
        if (key >= SEQ_) { kv0 = (uint4){0, 0, 0, 0}; kv1 = kv0; }
        int vk0 = kt * 64 + 2 * vp;
        int t0 = vk0 < SEQ_ ? vk0 : 0;
        int t1 = vk0 + 1 < SEQ_ ? vk0 + 1 : 0;
        va  = *(const uint4*)(qkv + ((size_t)(b * SEQ_ + t0)) * 1152 + 768 + hd * 64 + vdh);
        vb2 = *(const uint4*)(qkv + ((size_t)(b * SEQ_ + t1)) * 1152 + 768 + hd * 64 + vdh);
        if (vk0 >= SEQ_) va = (uint4){0, 0, 0, 0};
        if (vk0 + 1 >= SEQ_) vb2 = (uint4){0, 0, 0, 0};
    };

    loadKV(0);

    for (int kt = 0; kt < 10; kt++) {
        __syncthreads();
        *(uint4*)&Ks[skey][scol] = kv0;
        *(uint4*)&Ks[skey][scol + 8] = kv1;
        {
            const ushort_t* e0 = (const ushort_t*)&va;
            const ushort_t* e1 = (const ushort_t*)&vb2;
#pragma unroll
            for (int j = 0; j < 8; j++) {
                unsigned int pack = (unsigned int)e0[j] | ((unsigned int)e1[j] << 16);
                *(unsigned int*)&Vt[vdh + j][2 * vp] = pack;
            }
        }
        __syncthreads();
        if (kt + 1 < 10) loadKV(kt + 1);   // overlaps with compute below

        f32x4 s[4];
        __builtin_amdgcn_s_setprio(1);
#pragma unroll
        for (int ct = 0; ct < 4; ct++) {
            bf16x8 b0 = *(const bf16x8*)&Ks[ct * 16 + m16][q4 * 8];
            bf16x8 b1 = *(const bf16x8*)&Ks[ct * 16 + m16][32 + q4 * 8];
            f32x4 z = (f32x4){0.f, 0.f, 0.f, 0.f};
            z = __builtin_amdgcn_mfma_f32_16x16x32_bf16(qf0, b0, z, 0, 0, 0);
            z = __builtin_amdgcn_mfma_f32_16x16x32_bf16(qf1, b1, z, 0, 0, 0);
            s[ct] = z;
        }
        __builtin_amdgcn_s_setprio(0);
        const int rowb = qt * 64 + wv * 16 + q4 * 4;
#pragma unroll
        for (int r = 0; r < 4; r++) {
            float rs = 0.f;
#pragma unroll
            for (int ct = 0; ct < 4; ct++) {
                int col = kt * 64 + ct * 16 + m16;
                float v = s[ct][r] * sc2;
                if (col >= SEQ_ || col == rowb + r) v = -1.0e30f;
                float p = __builtin_amdgcn_exp2f(v);
                s[ct][r] = p;
                rs += p;
            }
            rs += __shfl_xor(rs, 1);
            rs += __shfl_xor(rs, 2);
            rs += __shfl_xor(rs, 4);
            rs += __shfl_xor(rs, 8);
            l_r[r] += rs;
        }
#pragma unroll
        for (int ct = 0; ct < 4; ct++)
#pragma unroll
            for (int r = 0; r < 4; r++)
                Pw[wv][q4 * 4 + r][ct * 16 + m16] = f2b(s[ct][r]);
        bf16x8 pf0 = *(const bf16x8*)&Pw[wv][m16][q4 * 8];
        bf16x8 pf1 = *(const bf16x8*)&Pw[wv][m16][32 + q4 * 8];
        __builtin_amdgcn_s_setprio(1);
#pragma unroll
        for (int dt = 0; dt < 4; dt++) {
            bf16x8 vb0 = *(const bf16x8*)&Vt[dt * 16 + m16][q4 * 8];
            bf16x8 vb1 = *(const bf16x8*)&Vt[dt * 16 + m16][32 + q4 * 8];
            f32x4 o = accO[dt];
            o = __builtin_amdgcn_mfma_f32_16x16x32_bf16(pf0, vb0, o, 0, 0, 0);
            o = __builtin_amdgcn_mfma_f32_16x16x32_bf16(pf1, vb1, o, 0, 0, 0);
            accO[dt] = o;
        }
        __builtin_amdgcn_s_setprio(0);
    }

    const int rowb = qt * 64 + wv * 16 + q4 * 4;
#pragma unroll
    for (int r = 0; r < 4; r++) {
        int grow = rowb + r;
        if (grow >= SEQ_) continue;
        float inv = 1.f / l_r[r];
        ushort_t* op = attn + ((size_t)(b * SEQ_ + grow)) * 384 + hd * 64;
#pragma unroll
        for (int dt = 0; dt < 4; dt++)
            op[dt * 16 + m16] = f2b(accO[dt][r] * inv);
    }
}

// ---------------------------------------------------------------------------
// SPT shift-gather + LayerNorm, plane-major (coalesced). One block = 1 patch.
// ---------------------------------------------------------------------------
__global__ __launch_bounds__(256) void spt_ln_kernel(
    const float* __restrict__ img, const float* __restrict__ gg,
    const float* __restrict__ bb_, ushort_t* __restrict__ Xn, int r0)
{
    int bp = r0 + blockIdx.x;
    int b = bp / 576, p = bp - b * 576;
    int ph = p / 24, pw = p - ph * 24;

    __shared__ float vals[3840];
    __shared__ float red[10];

    const int tid = threadIdx.x;
    const int p1 = tid >> 4, p2 = tid & 15;

    float s = 0.f, sq = 0.f;
#pragma unroll
    for (int plane = 0; plane < 15; plane++) {
        int g5 = plane / 3, ch = plane - g5 * 3;
        int row = ph * 16 + p1, col = pw * 16 + p2;
        if (g5 == 1) col -= 1;
        else if (g5 == 2) col += 1;
        else if (g5 == 3) row -= 1;
        else if (g5 == 4) row += 1;
        float v = 0.f;
        if (row >= 0 && row < 384 && col >= 0 && col < 384)
            v = img[((size_t)(b * 3 + ch) * 384 + row) * 384 + col];
        vals[tid * 15 + plane] = v;
        s += v; sq += v * v;
    }
#pragma unroll
    for (int off = 32; off > 0; off >>= 1) {
        s += __shfl_xor(s, off);
        sq += __shfl_xor(sq, off);
    }
    int wid = tid >> 6;
    if ((tid & 63) == 0) { red[wid] = s; red[4 + wid] = sq; }
    __syncthreads();
    if (tid == 0) {
        float S = red[0] + red[1] + red[2] + red[3];
        float Q = red[4] + red[5] + red[6] + red[7];
        float mean = S / 3840.f;
        float var = Q / 3840.f - mean * mean;
        red[8] = mean;
        red[9] = rsqrtf(var + 1e-5f);
    }
    __syncthreads();
    float mean = red[8], rstd = red[9];
#pragma unroll
    for (int i = 0; i < 15; i++) {
        int k = tid + i * 256;
        float v = (vals[k] - mean) * rstd * gg[k] + bb_[k];
        Xn[(size_t)blockIdx.x * 3840 + k] = f2b(v);
    }
}

// ---------------------------------------------------------------------------
// Per-token LayerNorm: 4 rows/block (1 wave each). Full-lane layout.
// ---------------------------------------------------------------------------
__global__ __launch_bounds__(256) void ln_kernel(
    const float* __restrict__ x, const float* __restrict__ g,
    const float* __restrict__ b, ushort_t* __restrict__ h)
{
    int row = blockIdx.x * 4 + (threadIdx.x >> 6);
    int lane = threadIdx.x & 63;
    const float* xr = x + (size_t)row * 384;
    float4 a = *(const float4*)(xr + lane * 4);
    float2 c = *(const float2*)(xr + 256 + lane * 2);
    float s = a.x + a.y + a.z + a.w + c.x + c.y;
    float sq = a.x * a.x + a.y * a.y + a.z * a.z + a.w * a.w
             + c.x * c.x + c.y * c.y;
#pragma unroll
    for (int off = 32; off > 0; off >>= 1) {
        s += __shfl_xor(s, off);
        sq += __shfl_xor(sq, off);
    }
    float mean = s / 384.f;
    float var = sq / 384.f - mean * mean;
    float rstd = rsqrtf(var + 1e-5f);
    float4 gv = *(const float4*)(g + lane * 4);
    float2 gc = *(const float2*)(g + 256 + lane * 2);
    float4 bv = *(const float4*)(b + lane * 4);
    float2 bc = *(const float2*)(b + 256 + lane * 2);
    ushort_t* hr = h + (size_t)row * 384;
    {
        unsigned int lo = (unsigned int)f2b((a.x - mean) * rstd * gv.x + bv.x)
                        | ((unsigned int)f2b((a.y - mean) * rstd * gv.y + bv.y) << 16);
        unsigned int hi = (unsigned int)f2b((a.z - mean) * rstd * gv.z + bv.z)
                        | ((unsigned int)f2b((a.w - mean) * rstd * gv.w + bv.w) << 16);
        *(uint2*)&hr[lane * 4] = make_uint2(lo, hi);
    }
    {
        unsigned int w = (unsigned int)f2b((c.x - mean) * rstd * gc.x + bc.x)
                       | ((unsigned int)f2b((c.y - mean) * rstd * gc.y + bc.y) << 16);
        *(unsigned int*)&hr[256 + lane * 2] = w;
    }
}

// ---------------------------------------------------------------------------
// Init residual: x[b,0,:] = cls + pos[0]; x[b,1+p,:] = spt_bias + pos[1+p].
// ---------------------------------------------------------------------------
__global__ void init_x_kernel(const float* __restrict__ cls,
                              const float* __restrict__ pos,
                              const float* __restrict__ spt_bias,
                              float* __restrict__ x)
{
    int s = blockIdx.x, b = blockIdx.y, d = threadIdx.x;
    float base = (s == 0) ? cls[d] : spt_bias[d];
    x[((size_t)b * SEQ_ + s) * D_ + d] = base + pos[(size_t)s * D_ + d];
}

// ---------------------------------------------------------------------------
extern "C" void kernel_launch(void* const* d_in, const int* in_sizes, int n_in,
                              void* d_out, int out_size, void* d_ws, size_t ws_size,
                              hipStream_t stream)
{
    const float* img      = (const float*)d_in[0];
    const float* spt_g    = (const float*)d_in[1];
    const float* spt_b    = (const float*)d_in[2];
    const float* spt_w    = (const float*)d_in[3];
    const float* spt_bias = (const float*)d_in[4];
    const float* pos      = (const float*)d_in[5];
    const float* clsp     = (const float*)d_in[6];
    const float* attn_g   = (const float*)d_in[7];
    const float* attn_b   = (const float*)d_in[8];
    const float* temp     = (const float*)d_in[9];
    const float* wqkv     = (const float*)d_in[10];
    const float* wout     = (const float*)d_in[11];
    const float* bout     = (const float*)d_in[12];
    const float* ff_g     = (const float*)d_in[13];
    const float* ff_b     = (const float*)d_in[14];
    const float* w1       = (const float*)d_in[15];
    const float* b1       = (const float*)d_in[16];
    const float* w2       = (const float*)d_in[17];
    const float* b2       = (const float*)d_in[18];

    float* x = (float*)d_out;   // residual f32 lives in d_out

    // ---- workspace layout ----
    char* base = (char*)d_ws;
    ushort_t* qkv   = (ushort_t*)base;
    ushort_t* attn  = (ushort_t*)(base + (size_t)NTOK * 1152 * 2);
    ushort_t* Xn    = (ushort_t*)base;
    ushort_t* gbuf  = (ushort_t*)base;
    ushort_t* spt_wt = (ushort_t*)(base + 23592960);
    char* p2 = base + (size_t)NTOK * 1536 * 2;         // 28,360,704
    ushort_t* h  = (ushort_t*)p2;                      // attn-LN output (7.09 MB)
    float* stats = (float*)p2;                         // ff-LN stats [NTOK][12][2]
                                                       // (aliases h: h dead after QKV,
                                                       //  stats dead after MLP1)
    char* p3 = p2 + (size_t)NTOK * 384 * 2;            // + 7,090,176
    ushort_t* W6 = (ushort_t*)p3;                      // + 21,233,664

    prep_all_kernel<<<2952, 256, 0, stream>>>(wqkv, wout, w1, w2, spt_w, W6, spt_wt);
    init_x_kernel<<<dim3(SEQ_, 16), 384, 0, stream>>>(clsp, pos, spt_bias, x);

    for (int c = 0; c < 3; c++) {
        int r0 = c * 3072;
        spt_ln_kernel<<<3072, 256, 0, stream>>>(img, spt_g, spt_b, Xn, r0);
        gemm64_spt_split<<<dim3(6, 48, 4), 256, 0, stream>>>(Xn, spt_wt, x, r0);
    }

    for (int l = 0; l < 6; l++) {
        ushort_t* qkv_t  = W6 + (size_t)l * 1769472;
        ushort_t* wout_t = qkv_t + 442368;
        ushort_t* w1_t   = wout_t + 147456;
        ushort_t* w2_t   = w1_t + 589824;
        ln_kernel<<<NTOK / 4, 256, 0, stream>>>(x, attn_g + l * 384, attn_b + l * 384, h);
        gemm12864<M_QKV, 12><<<dim3(18, 73), 256, 0, stream>>>(
            h, qkv_t, qkv, nullptr, NTOK, 1152);
        attn_kernel<<<dim3(10, 96), 256, 0, stream>>>(qkv, attn, temp, l);
        gemm64<M_OUT, 12><<<dim3(6, 145), 256, 0, stream>>>(
            attn, wout_t, x, bout + l * 384, stats, NTOK, 384);
        gemm12864_ln<12><<<dim3(24, 73), 256, 0, stream>>>(
            x, w1_t, gbuf, b1 + l * 1536, stats, ff_g + l * 384, ff_b + l * 384,
            NTOK, 1536);
        gemm64<M_MLP2, 48><<<dim3(6, 145), 256, 0, stream>>>(
            gbuf, w2_t, x, b2 + l * 384, nullptr, NTOK, 384);
    }
}

// Round 13
// 1112.262 us; speedup vs baseline: 1.1117x; 1.1117x over previous
//
#include <hip/hip_runtime.h>

typedef unsigned short ushort_t;
typedef __bf16 bf16x8 __attribute__((ext_vector_type(8)));
typedef float f32x4 __attribute__((ext_vector_type(4)));

#define SEQ_ 577
#define D_ 384
#define NTOK (16 * 577)   // 9232

enum { M_QKV = 0, M_OUT, M_MLP1, M_MLP2 };

__device__ inline float b2f(ushort_t u) {
    unsigned int x = ((unsigned int)u) << 16;
    float f; __builtin_memcpy(&f, &x, 4); return f;
}
__device__ inline ushort_t f2b(float f) {
    unsigned int x; __builtin_memcpy(&x, &f, 4);
    x = x + 0x7fffu + ((x >> 16) & 1u);
    return (ushort_t)(x >> 16);
}

// ---------------------------------------------------------------------------
// 64x64 tile transpose+convert: src f32 [K,N] (ld ldn) -> dst bf16 [N,K]
// ---------------------------------------------------------------------------
__device__ void transpose_tile(const float* __restrict__ src,
                               ushort_t* __restrict__ dst,
                               int ldn, int ldk, int k0, int n0)
{
    __shared__ float t[64][65];
    const int tid = threadIdx.x;
    const int c = tid & 63, rr = tid >> 6;
#pragma unroll
    for (int i = 0; i < 16; i++) {
        int kl = rr + i * 4;
        t[kl][c] = src[(size_t)(k0 + kl) * ldn + n0 + c];
    }
    __syncthreads();
#pragma unroll
    for (int i = 0; i < 16; i++) {
        int nl = rr + i * 4;
        dst[(size_t)(n0 + nl) * ldk + k0 + c] = f2b(t[c][nl]);
    }
}

// All 6 layers' weights + SPT weight in ONE dispatch: 6*432 + 360 = 2952 blocks.
__global__ __launch_bounds__(256) void prep_all_kernel(
    const float* __restrict__ wqkv, const float* __restrict__ wout,
    const float* __restrict__ w1, const float* __restrict__ w2,
    const float* __restrict__ spt_w,
    ushort_t* __restrict__ W6, ushort_t* __restrict__ spt_wt)
{
    int id = blockIdx.x;
    if (id >= 2592) {
        int r2 = id - 2592;                 // 360 blocks: 60 ktiles x 6 ntiles
        int kt = r2 % 60, nt = r2 / 60;
        transpose_tile(spt_w, spt_wt, 384, 3840, kt * 64, nt * 64);
        return;
    }
    int l = id / 432;
    int r = id - l * 432;
    ushort_t* qkv_t  = W6 + (size_t)l * 1769472;
    ushort_t* wout_t = qkv_t + 442368;
    ushort_t* w1_t   = wout_t + 147456;
    ushort_t* w2_t   = w1_t + 589824;
    const float* wq = wqkv + (size_t)l * 442368;
    const float* wo = wout + (size_t)l * 147456;
    const float* W1 = w1 + (size_t)l * 589824;
    const float* W2 = w2 + (size_t)l * 589824;
    if (r < 108) {
        int kt = r / 18, nt = r % 18;
        transpose_tile(wq, qkv_t, 1152, 384, kt * 64, nt * 64);
    } else if (r < 144) {
        r -= 108; int kt = r / 6, nt = r % 6;
        transpose_tile(wo, wout_t, 384, 384, kt * 64, nt * 64);
    } else if (r < 288) {
        r -= 144; int kt = r / 24, nt = r % 24;
        transpose_tile(W1, w1_t, 1536, 384, kt * 64, nt * 64);
    } else {
        r -= 288; int kt = r / 6, nt = r % 6;
        transpose_tile(W2, w2_t, 384, 1536, kt * 64, nt * 64);
    }
}

// ---------------------------------------------------------------------------
// 128x64-tile distance-2 pipelined GEMM for wide-N ops (QKV, MLP1).
// 256 threads = 4 waves, each wave 64x32 (4x2 of 16x16x32 bf16).
// Compile-time NK: K-loop fully unrolled (guards fold to constants).
// Bijective chunked XCD swizzle. M-tail loads unguarded, stores guarded.
// ---------------------------------------------------------------------------
template <int MODE, int NK>
__global__ __launch_bounds__(256) void gemm12864(
    const ushort_t* __restrict__ A, const ushort_t* __restrict__ Bt,
    ushort_t* __restrict__ Co, const float* __restrict__ bias,
    int M, int ldc)
{
    const int K = NK * 32;
    __shared__ __align__(16) ushort_t As[2][128][40];
    __shared__ __align__(16) ushort_t Bs[2][64][40];

    const int gx = gridDim.x;
    const int nwg = gx * gridDim.y;
    const int f = blockIdx.y * gx + blockIdx.x;
    const int q = nwg >> 3, rr_ = nwg & 7;
    const int xcd = f & 7, ii = f >> 3;
    const int swz = (xcd < rr_ ? xcd * (q + 1) : rr_ * (q + 1) + (xcd - rr_) * q) + ii;
    const int bx = swz % gx, by = swz / gx;

    const int tid = threadIdx.x;
    const int rowBase = by * 128;
    const int colBase = bx * 64;
    const int lr = tid >> 2, lk = (tid & 3) * 8;
    const int wv = tid >> 6, lane = tid & 63;
    const int wm = (wv >> 1) * 64, wn = (wv & 1) * 32;
    const int m16 = lane & 15, q4 = lane >> 4, kb = q4 * 8;

    const ushort_t* pa0 = A + (size_t)(rowBase + lr) * K + lk;
    const ushort_t* pa1 = pa0 + (size_t)64 * K;
    const ushort_t* pb  = Bt + (size_t)(colBase + lr) * K + lk;

    f32x4 acc[4][2];
#pragma unroll
    for (int i = 0; i < 4; i++)
#pragma unroll
        for (int j = 0; j < 2; j++) acc[i][j] = (f32x4){0.f, 0.f, 0.f, 0.f};

    uint4 Ua0, Ua1, Ub, Va0, Va1, Vb;
    auto gloadU = [&](int kt) {
        Ua0 = *(const uint4*)(pa0 + kt * 32);
        Ua1 = *(const uint4*)(pa1 + kt * 32);
        Ub  = *(const uint4*)(pb + kt * 32);
    };
    auto gloadV = [&](int kt) {
        Va0 = *(const uint4*)(pa0 + kt * 32);
        Va1 = *(const uint4*)(pa1 + kt * 32);
        Vb  = *(const uint4*)(pb + kt * 32);
    };
    auto swriteU = [&](int buf) {
        *(uint4*)&As[buf][lr][lk] = Ua0;
        *(uint4*)&As[buf][64 + lr][lk] = Ua1;
        *(uint4*)&Bs[buf][lr][lk] = Ub;
    };
    auto swriteV = [&](int buf) {
        *(uint4*)&As[buf][lr][lk] = Va0;
        *(uint4*)&As[buf][64 + lr][lk] = Va1;
        *(uint4*)&Bs[buf][lr][lk] = Vb;
    };
    auto compute = [&](int buf) {
        bf16x8 af[4];
#pragma unroll
        for (int mt = 0; mt < 4; mt++)
            af[mt] = *(const bf16x8*)&As[buf][wm + mt * 16 + m16][kb];
        bf16x8 b0 = *(const bf16x8*)&Bs[buf][wn + m16][kb];
        bf16x8 b1 = *(const bf16x8*)&Bs[buf][wn + 16 + m16][kb];
#pragma unroll
        for (int mt = 0; mt < 4; mt++) {
            acc[mt][0] = __builtin_amdgcn_mfma_f32_16x16x32_bf16(af[mt], b0, acc[mt][0], 0, 0, 0);
            acc[mt][1] = __builtin_amdgcn_mfma_f32_16x16x32_bf16(af[mt], b1, acc[mt][1], 0, 0, 0);
        }
    };

    gloadU(0);
    swriteU(0);
    gloadU(1);
    gloadV(2);
    __syncthreads();

#pragma unroll
    for (int kt = 0; kt < NK; kt += 2) {
        swriteU(1);
        if (kt + 3 < NK) gloadU(kt + 3);
        compute(0);
        __syncthreads();
        if (kt + 2 < NK) {
            swriteV(0);
            if (kt + 4 < NK) gloadV(kt + 4);
        }
        compute(1);
        __syncthreads();
    }

#pragma unroll
    for (int mt = 0; mt < 4; mt++)
#pragma unroll
        for (int nt = 0; nt < 2; nt++) {
            int col = colBase + wn + nt * 16 + m16;
#pragma unroll
            for (int r = 0; r < 4; r++) {
                int row = rowBase + wm + mt * 16 + q4 * 4 + r;
                if (row >= M) continue;
                float v = acc[mt][nt][r];
                if (MODE == M_QKV) {
                    Co[(size_t)row * ldc + col] = f2b(v);
                } else if (MODE == M_MLP1) {
                    float t = v + bias[col];
                    float u = t * (0.7978845608f + 0.0356774081f * t * t);
                    float e = __builtin_amdgcn_exp2f(2.885390082f * u);
                    float gl = t - t * __builtin_amdgcn_rcpf(e + 1.0f);
                    Co[(size_t)row * ldc + col] = f2b(gl);
                }
            }
        }
}

// ---------------------------------------------------------------------------
// 64x64-tile distance-2 pipelined GEMM (OUT / MLP2).
// resid f32 += v + bias epilogue. Compile-time NK (full unroll).
// Bijective chunked XCD swizzle.
// ---------------------------------------------------------------------------
template <int MODE, int NK>
__global__ __launch_bounds__(256) void gemm64(
    const ushort_t* __restrict__ A, const ushort_t* __restrict__ Bt,
    float* __restrict__ resid, const float* __restrict__ bias,
    int M, int ldc)
{
    const int K = NK * 32;
    __shared__ __align__(16) ushort_t As[2][64][40];
    __shared__ __align__(16) ushort_t Bs[2][64][40];

    const int gx = gridDim.x, gy = gridDim.y;
    const int nwg = gx * gy;
    const int f = blockIdx.y * gx + blockIdx.x;
    const int q = nwg >> 3, rr_ = nwg & 7;
    const int xcd = f & 7, ii = f >> 3;
    const int swz = (xcd < rr_ ? xcd * (q + 1) : rr_ * (q + 1) + (xcd - rr_) * q) + ii;
    const int bx = swz % gx, by = swz / gx;

    const int tid = threadIdx.x;
    const int rowBase = by * 64;
    const int colBase = bx * 64;
    const int lr = tid >> 2, lk = (tid & 3) * 8;
    const int wv = tid >> 6, lane = tid & 63;
    const int wm = (wv >> 1) * 32, wn = (wv & 1) * 32;
    const int m16 = lane & 15, q4 = lane >> 4, kb = q4 * 8;

    const ushort_t* pa = A + (size_t)(rowBase + lr) * K + lk;
    const ushort_t* pb = Bt + (size_t)(colBase + lr) * K + lk;

    f32x4 acc[2][2];
#pragma unroll
    for (int i = 0; i < 2; i++)
#pragma unroll
        for (int j = 0; j < 2; j++) acc[i][j] = (f32x4){0.f, 0.f, 0.f, 0.f};

    uint4 Ua, Ub, Va, Vb;
    auto gloadU = [&](int kt) {
        Ua = *(const uint4*)(pa + kt * 32);
        Ub = *(const uint4*)(pb + kt * 32);
    };
    auto gloadV = [&](int kt) {
        Va = *(const uint4*)(pa + kt * 32);
        Vb = *(const uint4*)(pb + kt * 32);
    };
    auto swriteU = [&](int buf) {
        *(uint4*)&As[buf][lr][lk] = Ua;
        *(uint4*)&Bs[buf][lr][lk] = Ub;
    };
    auto swriteV = [&](int buf) {
        *(uint4*)&As[buf][lr][lk] = Va;
        *(uint4*)&Bs[buf][lr][lk] = Vb;
    };
    auto compute = [&](int buf) {
        bf16x8 a0 = *(const bf16x8*)&As[buf][wm + m16][kb];
        bf16x8 a1 = *(const bf16x8*)&As[buf][wm + 16 + m16][kb];
        bf16x8 b0 = *(const bf16x8*)&Bs[buf][wn + m16][kb];
        bf16x8 b1 = *(const bf16x8*)&Bs[buf][wn + 16 + m16][kb];
        acc[0][0] = __builtin_amdgcn_mfma_f32_16x16x32_bf16(a0, b0, acc[0][0], 0, 0, 0);
        acc[0][1] = __builtin_amdgcn_mfma_f32_16x16x32_bf16(a0, b1, acc[0][1], 0, 0, 0);
        acc[1][0] = __builtin_amdgcn_mfma_f32_16x16x32_bf16(a1, b0, acc[1][0], 0, 0, 0);
        acc[1][1] = __builtin_amdgcn_mfma_f32_16x16x32_bf16(a1, b1, acc[1][1], 0, 0, 0);
    };

    gloadU(0);
    swriteU(0);
    gloadU(1);
    gloadV(2);
    __syncthreads();

#pragma unroll
    for (int kt = 0; kt < NK; kt += 2) {
        swriteU(1);
        if (kt + 3 < NK) gloadU(kt + 3);
        compute(0);
        __syncthreads();
        if (kt + 2 < NK) {
            swriteV(0);
            if (kt + 4 < NK) gloadV(kt + 4);
        }
        compute(1);
        __syncthreads();
    }

#pragma unroll
    for (int im = 0; im < 2; im++)
#pragma unroll
        for (int in = 0; in < 2; in++) {
            int col = colBase + wn + in * 16 + m16;
#pragma unroll
            for (int r = 0; r < 4; r++) {
                int row = rowBase + wm + im * 16 + q4 * 4 + r;
                if (row >= M) continue;
                size_t o = (size_t)row * ldc + col;
                resid[o] = resid[o] + acc[im][in][r] + bias[col];
            }
        }
}

// ---------------------------------------------------------------------------
// Split-K (z=4) depth-2 double-buffered 64x64 GEMM for the SPT embed.
// Grid (6,48,4) = 1152 blocks, nk=30 per split. atomicAdd partials into
// resid (pre-initialized with spt_bias + pos). Chunked XCD swizzle.
// ---------------------------------------------------------------------------
__global__ __launch_bounds__(256) void gemm64_spt_split(
    const ushort_t* __restrict__ A, const ushort_t* __restrict__ Bt,
    float* __restrict__ resid, int rowOff)
{
    __shared__ __align__(16) ushort_t As[2][64][40];
    __shared__ __align__(16) ushort_t Bs[2][64][40];

    const int f = blockIdx.z * 288 + blockIdx.y * 6 + blockIdx.x;
    const int swz = (f & 7) * 144 + (f >> 3);
    const int bz = swz / 288;
    const int rem = swz - bz * 288;
    const int by = rem / 6, bx = rem - by * 6;

    const int K = 3840, nk = 30;
    const int rowBase = by * 64;
    const int colBase = bx * 64;
    const int kbase = bz * 960;

    const int tid = threadIdx.x;
    const int lr = tid >> 2, lk = (tid & 3) * 8;
    const int wv = tid >> 6, lane = tid & 63;
    const int wm = (wv >> 1) * 32, wn = (wv & 1) * 32;
    const int m16 = lane & 15, q4 = lane >> 4, kb = q4 * 8;

    const ushort_t* pa = A + (size_t)(rowBase + lr) * K + kbase + lk;
    const ushort_t* pb = Bt + (size_t)(colBase + lr) * K + kbase + lk;

    f32x4 acc[2][2];
#pragma unroll
    for (int i = 0; i < 2; i++)
#pragma unroll
        for (int j = 0; j < 2; j++) acc[i][j] = (f32x4){0.f, 0.f, 0.f, 0.f};

    uint4 Ua, Ub, Va, Vb;
    auto gloadU = [&](int kt) {
        Ua = *(const uint4*)(pa + kt * 32);
        Ub = *(const uint4*)(pb + kt * 32);
    };
    auto gloadV = [&](int kt) {
        Va = *(const uint4*)(pa + kt * 32);
        Vb = *(const uint4*)(pb + kt * 32);
    };
    auto swriteU = [&](int buf) {
        *(uint4*)&As[buf][lr][lk] = Ua;
        *(uint4*)&Bs[buf][lr][lk] = Ub;
    };
    auto swriteV = [&](int buf) {
        *(uint4*)&As[buf][lr][lk] = Va;
        *(uint4*)&Bs[buf][lr][lk] = Vb;
    };
    auto compute = [&](int buf) {
        bf16x8 a0 = *(const bf16x8*)&As[buf][wm + m16][kb];
        bf16x8 a1 = *(const bf16x8*)&As[buf][wm + 16 + m16][kb];
        bf16x8 b0 = *(const bf16x8*)&Bs[buf][wn + m16][kb];
        bf16x8 b1 = *(const bf16x8*)&Bs[buf][wn + 16 + m16][kb];
        acc[0][0] = __builtin_amdgcn_mfma_f32_16x16x32_bf16(a0, b0, acc[0][0], 0, 0, 0);
        acc[0][1] = __builtin_amdgcn_mfma_f32_16x16x32_bf16(a0, b1, acc[0][1], 0, 0, 0);
        acc[1][0] = __builtin_amdgcn_mfma_f32_16x16x32_bf16(a1, b0, acc[1][0], 0, 0, 0);
        acc[1][1] = __builtin_amdgcn_mfma_f32_16x16x32_bf16(a1, b1, acc[1][1], 0, 0, 0);
    };

    gloadU(0);
    swriteU(0);
    gloadU(1);
    gloadV(2);
    __syncthreads();

    for (int kt = 0; kt < nk; kt += 2) {
        swriteU(1);
        if (kt + 3 < nk) gloadU(kt + 3);
        compute(0);
        __syncthreads();
        if (kt + 2 < nk) {
            swriteV(0);
            if (kt + 4 < nk) gloadV(kt + 4);
        }
        compute(1);
        __syncthreads();
    }

#pragma unroll
    for (int im = 0; im < 2; im++)
#pragma unroll
        for (int in = 0; in < 2; in++) {
            int col = colBase + wn + in * 16 + m16;
#pragma unroll
            for (int r = 0; r < 4; r++) {
                int row = rowBase + wm + im * 16 + q4 * 4 + r;
                int grow = rowOff + row;
                int bb = grow / 576, p = grow - bb * 576;
                size_t o = ((size_t)(bb * SEQ_ + 1 + p)) * D_ + col;
                atomicAdd(&resid[o], acc[im][in][r]);
            }
        }
}

// ---------------------------------------------------------------------------
// Fused flash attention (one layer). Grid (10 qtiles, 96 b*h), 256 thr.
// Chunked XCD swizzle + one-iteration load-ahead + setprio on MFMA clusters.
// ---------------------------------------------------------------------------
__global__ __launch_bounds__(256) void attn_kernel(
    const ushort_t* __restrict__ qkv, ushort_t* __restrict__ attn,
    const float* __restrict__ temp, int layer)
{
    const int f = blockIdx.y * 10 + blockIdx.x;          // 960 blocks, 960%8==0
    const int swz = (f & 7) * 120 + (f >> 3);            // chunked XCD swizzle
    const int qt = swz % 10;
    const int bh = swz / 10;
    const int b = bh / 6, hd = bh - b * 6;
    const int tid = threadIdx.x;
    const int wv = tid >> 6, lane = tid & 63;
    const int m16 = lane & 15, q4 = lane >> 4;
    const float sc2 = expf(temp[layer]) * 1.44269504f;

    __shared__ __align__(16) ushort_t Ks[64][72];
    __shared__ __align__(16) ushort_t Vt[64][72];
    __shared__ __align__(16) ushort_t Pw[4][16][72];

    const int qrow = qt * 64 + wv * 16 + m16;
    const int qtok = qrow < SEQ_ ? qrow : SEQ_ - 1;
    const ushort_t* qb = qkv + ((size_t)(b * SEQ_ + qtok)) * 1152 + hd * 64;
    bf16x8 qf0 = *(const bf16x8*)(qb + q4 * 8);
    bf16x8 qf1 = *(const bf16x8*)(qb + 32 + q4 * 8);

    f32x4 accO[4];
#pragma unroll
    for (int dt = 0; dt < 4; dt++) accO[dt] = (f32x4){0.f, 0.f, 0.f, 0.f};
    float l_r[4] = {0.f, 0.f, 0.f, 0.f};

    const int skey = tid >> 2;
    const int scol = (tid & 3) * 16;
    const int vp   = tid & 31;
    const int vdh  = (tid >> 5) * 8;

    uint4 kv0, kv1, va, vb2;
    auto loadKV = [&](int kt) {
        int key = kt * 64 + skey;
        int gkey = key < SEQ_ ? key : 0;
        const ushort_t* kb_ = qkv + ((size_t)(b * SEQ_ + gkey)) * 1152 + 384 + hd * 64;
        kv0 = *(const uint4*)(kb_ + scol);
        kv1 = *(const uint4*)(kb_ + scol + 8);
        if (key >= SEQ_) { kv0 = (uint4){0, 0, 0, 0}; kv1 = kv0; }
        int vk0 = kt * 64 + 2 * vp;
        int t0 = vk0 < SEQ_ ? vk0 : 0;
        int t1 = vk0 + 1 < SEQ_ ? vk0 + 1 : 0;
        va  = *(const uint4*)(qkv + ((size_t)(b * SEQ_ + t0)) * 1152 + 768 + hd * 64 + vdh);
        vb2 = *(const uint4*)(qkv + ((size_t)(b * SEQ_ + t1)) * 1152 + 768 + hd * 64 + vdh);
        if (vk0 >= SEQ_) va = (uint4){0, 0, 0, 0};
        if (vk0 + 1 >= SEQ_) vb2 = (uint4){0, 0, 0, 0};
    };

    loadKV(0);

    for (int kt = 0; kt < 10; kt++) {
        __syncthreads();
        *(uint4*)&Ks[skey][scol] = kv0;
        *(uint4*)&Ks[skey][scol + 8] = kv1;
        {
            const ushort_t* e0 = (const ushort_t*)&va;
            const ushort_t* e1 = (const ushort_t*)&vb2;
#pragma unroll
            for (int j = 0; j < 8; j++) {
                unsigned int pack = (unsigned int)e0[j] | ((unsigned int)e1[j] << 16);
                *(unsigned int*)&Vt[vdh + j][2 * vp] = pack;
            }
        }
        __syncthreads();
        if (kt + 1 < 10) loadKV(kt + 1);   // overlaps with compute below

        f32x4 s[4];
        __builtin_amdgcn_s_setprio(1);
#pragma unroll
        for (int ct = 0; ct < 4; ct++) {
            bf16x8 b0 = *(const bf16x8*)&Ks[ct * 16 + m16][q4 * 8];
            bf16x8 b1 = *(const bf16x8*)&Ks[ct * 16 + m16][32 + q4 * 8];
            f32x4 z = (f32x4){0.f, 0.f, 0.f, 0.f};
            z = __builtin_amdgcn_mfma_f32_16x16x32_bf16(qf0, b0, z, 0, 0, 0);
            z = __builtin_amdgcn_mfma_f32_16x16x32_bf16(qf1, b1, z, 0, 0, 0);
            s[ct] = z;
        }
        __builtin_amdgcn_s_setprio(0);
        const int rowb = qt * 64 + wv * 16 + q4 * 4;
#pragma unroll
        for (int r = 0; r < 4; r++) {
            float rs = 0.f;
#pragma unroll
            for (int ct = 0; ct < 4; ct++) {
                int col = kt * 64 + ct * 16 + m16;
                float v = s[ct][r] * sc2;
                if (col >= SEQ_ || col == rowb + r) v = -1.0e30f;
                float p = __builtin_amdgcn_exp2f(v);
                s[ct][r] = p;
                rs += p;
            }
            rs += __shfl_xor(rs, 1);
            rs += __shfl_xor(rs, 2);
            rs += __shfl_xor(rs, 4);
            rs += __shfl_xor(rs, 8);
            l_r[r] += rs;
        }
#pragma unroll
        for (int ct = 0; ct < 4; ct++)
#pragma unroll
            for (int r = 0; r < 4; r++)
                Pw[wv][q4 * 4 + r][ct * 16 + m16] = f2b(s[ct][r]);
        bf16x8 pf0 = *(const bf16x8*)&Pw[wv][m16][q4 * 8];
        bf16x8 pf1 = *(const bf16x8*)&Pw[wv][m16][32 + q4 * 8];
        __builtin_amdgcn_s_setprio(1);
#pragma unroll
        for (int dt = 0; dt < 4; dt++) {
            bf16x8 vb0 = *(const bf16x8*)&Vt[dt * 16 + m16][q4 * 8];
            bf16x8 vb1 = *(const bf16x8*)&Vt[dt * 16 + m16][32 + q4 * 8];
            f32x4 o = accO[dt];
            o = __builtin_amdgcn_mfma_f32_16x16x32_bf16(pf0, vb0, o, 0, 0, 0);
            o = __builtin_amdgcn_mfma_f32_16x16x32_bf16(pf1, vb1, o, 0, 0, 0);
            accO[dt] = o;
        }
        __builtin_amdgcn_s_setprio(0);
    }

    const int rowb = qt * 64 + wv * 16 + q4 * 4;
#pragma unroll
    for (int r = 0; r < 4; r++) {
        int grow = rowb + r;
        if (grow >= SEQ_) continue;
        float inv = 1.f / l_r[r];
        ushort_t* op = attn + ((size_t)(b * SEQ_ + grow)) * 384 + hd * 64;
#pragma unroll
        for (int dt = 0; dt < 4; dt++)
            op[dt * 16 + m16] = f2b(accO[dt][r] * inv);
    }
}

// ---------------------------------------------------------------------------
// SPT shift-gather + LayerNorm, plane-major (coalesced). One block = 1 patch.
// ---------------------------------------------------------------------------
__global__ __launch_bounds__(256) void spt_ln_kernel(
    const float* __restrict__ img, const float* __restrict__ gg,
    const float* __restrict__ bb_, ushort_t* __restrict__ Xn, int r0)
{
    int bp = r0 + blockIdx.x;
    int b = bp / 576, p = bp - b * 576;
    int ph = p / 24, pw = p - ph * 24;

    __shared__ float vals[3840];
    __shared__ float red[10];

    const int tid = threadIdx.x;
    const int p1 = tid >> 4, p2 = tid & 15;

    float s = 0.f, sq = 0.f;
#pragma unroll
    for (int plane = 0; plane < 15; plane++) {
        int g5 = plane / 3, ch = plane - g5 * 3;
        int row = ph * 16 + p1, col = pw * 16 + p2;
        if (g5 == 1) col -= 1;
        else if (g5 == 2) col += 1;
        else if (g5 == 3) row -= 1;
        else if (g5 == 4) row += 1;
        float v = 0.f;
        if (row >= 0 && row < 384 && col >= 0 && col < 384)
            v = img[((size_t)(b * 3 + ch) * 384 + row) * 384 + col];
        vals[tid * 15 + plane] = v;
        s += v; sq += v * v;
    }
#pragma unroll
    for (int off = 32; off > 0; off >>= 1) {
        s += __shfl_xor(s, off);
        sq += __shfl_xor(sq, off);
    }
    int wid = tid >> 6;
    if ((tid & 63) == 0) { red[wid] = s; red[4 + wid] = sq; }
    __syncthreads();
    if (tid == 0) {
        float S = red[0] + red[1] + red[2] + red[3];
        float Q = red[4] + red[5] + red[6] + red[7];
        float mean = S / 3840.f;
        float var = Q / 3840.f - mean * mean;
        red[8] = mean;
        red[9] = rsqrtf(var + 1e-5f);
    }
    __syncthreads();
    float mean = red[8], rstd = red[9];
#pragma unroll
    for (int i = 0; i < 15; i++) {
        int k = tid + i * 256;
        float v = (vals[k] - mean) * rstd * gg[k] + bb_[k];
        Xn[(size_t)blockIdx.x * 3840 + k] = f2b(v);
    }
}

// ---------------------------------------------------------------------------
// Per-token LayerNorm: 4 rows/block (1 wave each). Full-lane layout:
// each lane owns float4 @ 4*lane + float2 @ 256+2*lane (no divergent
// half-wave tranche; all loads/stores coalesced).
// ---------------------------------------------------------------------------
__global__ __launch_bounds__(256) void ln_kernel(
    const float* __restrict__ x, const float* __restrict__ g,
    const float* __restrict__ b, ushort_t* __restrict__ h)
{
    int row = blockIdx.x * 4 + (threadIdx.x >> 6);
    int lane = threadIdx.x & 63;
    const float* xr = x + (size_t)row * 384;
    float4 a = *(const float4*)(xr + lane * 4);
    float2 c = *(const float2*)(xr + 256 + lane * 2);
    float s = a.x + a.y + a.z + a.w + c.x + c.y;
    float sq = a.x * a.x + a.y * a.y + a.z * a.z + a.w * a.w
             + c.x * c.x + c.y * c.y;
#pragma unroll
    for (int off = 32; off > 0; off >>= 1) {
        s += __shfl_xor(s, off);
        sq += __shfl_xor(sq, off);
    }
    float mean = s / 384.f;
    float var = sq / 384.f - mean * mean;
    float rstd = rsqrtf(var + 1e-5f);
    float4 gv = *(const float4*)(g + lane * 4);
    float2 gc = *(const float2*)(g + 256 + lane * 2);
    float4 bv = *(const float4*)(b + lane * 4);
    float2 bc = *(const float2*)(b + 256 + lane * 2);
    ushort_t* hr = h + (size_t)row * 384;
    {
        unsigned int lo = (unsigned int)f2b((a.x - mean) * rstd * gv.x + bv.x)
                        | ((unsigned int)f2b((a.y - mean) * rstd * gv.y + bv.y) << 16);
        unsigned int hi = (unsigned int)f2b((a.z - mean) * rstd * gv.z + bv.z)
                        | ((unsigned int)f2b((a.w - mean) * rstd * gv.w + bv.w) << 16);
        *(uint2*)&hr[lane * 4] = make_uint2(lo, hi);
    }
    {
        unsigned int w = (unsigned int)f2b((c.x - mean) * rstd * gc.x + bc.x)
                       | ((unsigned int)f2b((c.y - mean) * rstd * gc.y + bc.y) << 16);
        *(unsigned int*)&hr[256 + lane * 2] = w;
    }
}

// ---------------------------------------------------------------------------
// Init residual: x[b,0,:] = cls + pos[0]; x[b,1+p,:] = spt_bias + pos[1+p].
// ---------------------------------------------------------------------------
__global__ void init_x_kernel(const float* __restrict__ cls,
                              const float* __restrict__ pos,
                              const float* __restrict__ spt_bias,
                              float* __restrict__ x)
{
    int s = blockIdx.x, b = blockIdx.y, d = threadIdx.x;
    float base = (s == 0) ? cls[d] : spt_bias[d];
    x[((size_t)b * SEQ_ + s) * D_ + d] = base + pos[(size_t)s * D_ + d];
}

// ---------------------------------------------------------------------------
extern "C" void kernel_launch(void* const* d_in, const int* in_sizes, int n_in,
                              void* d_out, int out_size, void* d_ws, size_t ws_size,
                              hipStream_t stream)
{
    const float* img      = (const float*)d_in[0];
    const float* spt_g    = (const float*)d_in[1];
    const float* spt_b    = (const float*)d_in[2];
    const float* spt_w    = (const float*)d_in[3];
    const float* spt_bias = (const float*)d_in[4];
    const float* pos      = (const float*)d_in[5];
    const float* clsp     = (const float*)d_in[6];
    const float* attn_g   = (const float*)d_in[7];
    const float* attn_b   = (const float*)d_in[8];
    const float* temp     = (const float*)d_in[9];
    const float* wqkv     = (const float*)d_in[10];
    const float* wout     = (const float*)d_in[11];
    const float* bout     = (const float*)d_in[12];
    const float* ff_g     = (const float*)d_in[13];
    const float* ff_b     = (const float*)d_in[14];
    const float* w1       = (const float*)d_in[15];
    const float* b1       = (const float*)d_in[16];
    const float* w2       = (const float*)d_in[17];
    const float* b2       = (const float*)d_in[18];

    float* x = (float*)d_out;   // residual f32 lives in d_out

    // ---- workspace layout ----
    char* base = (char*)d_ws;
    ushort_t* qkv   = (ushort_t*)base;
    ushort_t* attn  = (ushort_t*)(base + (size_t)NTOK * 1152 * 2);
    ushort_t* Xn    = (ushort_t*)base;
    ushort_t* gbuf  = (ushort_t*)base;
    ushort_t* spt_wt = (ushort_t*)(base + 23592960);
    char* p2 = base + (size_t)NTOK * 1536 * 2;         // 28,360,704
    ushort_t* h  = (ushort_t*)p2;
    char* p3 = p2 + (size_t)NTOK * 384 * 2;            // + 7,090,176
    ushort_t* W6 = (ushort_t*)p3;                      // + 21,233,664

    prep_all_kernel<<<2952, 256, 0, stream>>>(wqkv, wout, w1, w2, spt_w, W6, spt_wt);
    init_x_kernel<<<dim3(SEQ_, 16), 384, 0, stream>>>(clsp, pos, spt_bias, x);

    for (int c = 0; c < 3; c++) {
        int r0 = c * 3072;
        spt_ln_kernel<<<3072, 256, 0, stream>>>(img, spt_g, spt_b, Xn, r0);
        gemm64_spt_split<<<dim3(6, 48, 4), 256, 0, stream>>>(Xn, spt_wt, x, r0);
    }

    for (int l = 0; l < 6; l++) {
        ushort_t* qkv_t  = W6 + (size_t)l * 1769472;
        ushort_t* wout_t = qkv_t + 442368;
        ushort_t* w1_t   = wout_t + 147456;
        ushort_t* w2_t   = w1_t + 589824;
        ln_kernel<<<NTOK / 4, 256, 0, stream>>>(x, attn_g + l * 384, attn_b + l * 384, h);
        gemm12864<M_QKV, 12><<<dim3(18, 73), 256, 0, stream>>>(
            h, qkv_t, qkv, nullptr, NTOK, 1152);
        attn_kernel<<<dim3(10, 96), 256, 0, stream>>>(qkv, attn, temp, l);
        gemm64<M_OUT, 12><<<dim3(6, 145), 256, 0, stream>>>(
            attn, wout_t, x, bout + l * 384, NTOK, 384);
        ln_kernel<<<NTOK / 4, 256, 0, stream>>>(x, ff_g + l * 384, ff_b + l * 384, h);
        gemm12864<M_MLP1, 12><<<dim3(24, 73), 256, 0, stream>>>(
            h, w1_t, gbuf, b1 + l * 1536, NTOK, 1536);
        gemm64<M_MLP2, 48><<<dim3(6, 145), 256, 0, stream>>>(
            gbuf, w2_t, x, b2 + l * 384, NTOK, 384);
    }
}

// Round 14
// 1097.763 us; speedup vs baseline: 1.1264x; 1.0132x over previous
//
#include <hip/hip_runtime.h>

typedef unsigned short ushort_t;
typedef __bf16 bf16x8 __attribute__((ext_vector_type(8)));
typedef float f32x4 __attribute__((ext_vector_type(4)));

#define SEQ_ 577
#define D_ 384
#define NTOK (16 * 577)   // 9232

enum { M_QKV = 0, M_OUT, M_MLP1, M_MLP2 };

__device__ inline float b2f(ushort_t u) {
    unsigned int x = ((unsigned int)u) << 16;
    float f; __builtin_memcpy(&f, &x, 4); return f;
}
__device__ inline ushort_t f2b(float f) {
    unsigned int x; __builtin_memcpy(&x, &f, 4);
    x = x + 0x7fffu + ((x >> 16) & 1u);
    return (ushort_t)(x >> 16);
}

// ---------------------------------------------------------------------------
// 64x64 tile transpose+convert: src f32 [K,N] (ld ldn) -> dst bf16 [N,K]
// ---------------------------------------------------------------------------
__device__ void transpose_tile(const float* __restrict__ src,
                               ushort_t* __restrict__ dst,
                               int ldn, int ldk, int k0, int n0)
{
    __shared__ float t[64][65];
    const int tid = threadIdx.x;
    const int c = tid & 63, rr = tid >> 6;
#pragma unroll
    for (int i = 0; i < 16; i++) {
        int kl = rr + i * 4;
        t[kl][c] = src[(size_t)(k0 + kl) * ldn + n0 + c];
    }
    __syncthreads();
#pragma unroll
    for (int i = 0; i < 16; i++) {
        int nl = rr + i * 4;
        dst[(size_t)(n0 + nl) * ldk + k0 + c] = f2b(t[c][nl]);
    }
}

// All 6 layers' weights + SPT weight in ONE dispatch: 6*432 + 360 = 2952 blocks.
__global__ __launch_bounds__(256) void prep_all_kernel(
    const float* __restrict__ wqkv, const float* __restrict__ wout,
    const float* __restrict__ w1, const float* __restrict__ w2,
    const float* __restrict__ spt_w,
    ushort_t* __restrict__ W6, ushort_t* __restrict__ spt_wt)
{
    int id = blockIdx.x;
    if (id >= 2592) {
        int r2 = id - 2592;                 // 360 blocks: 60 ktiles x 6 ntiles
        int kt = r2 % 60, nt = r2 / 60;
        transpose_tile(spt_w, spt_wt, 384, 3840, kt * 64, nt * 64);
        return;
    }
    int l = id / 432;
    int r = id - l * 432;
    ushort_t* qkv_t  = W6 + (size_t)l * 1769472;
    ushort_t* wout_t = qkv_t + 442368;
    ushort_t* w1_t   = wout_t + 147456;
    ushort_t* w2_t   = w1_t + 589824;
    const float* wq = wqkv + (size_t)l * 442368;
    const float* wo = wout + (size_t)l * 147456;
    const float* W1 = w1 + (size_t)l * 589824;
    const float* W2 = w2 + (size_t)l * 589824;
    if (r < 108) {
        int kt = r / 18, nt = r % 18;
        transpose_tile(wq, qkv_t, 1152, 384, kt * 64, nt * 64);
    } else if (r < 144) {
        r -= 108; int kt = r / 6, nt = r % 6;
        transpose_tile(wo, wout_t, 384, 384, kt * 64, nt * 64);
    } else if (r < 288) {
        r -= 144; int kt = r / 24, nt = r % 24;
        transpose_tile(W1, w1_t, 1536, 384, kt * 64, nt * 64);
    } else {
        r -= 288; int kt = r / 6, nt = r % 6;
        transpose_tile(W2, w2_t, 384, 1536, kt * 64, nt * 64);
    }
}

// ---------------------------------------------------------------------------
// 128x64-tile distance-2 pipelined GEMM for wide-N ops (QKV, MLP1).
// 256 threads = 4 waves, each wave 64x32 (4x2 of 16x16x32 bf16).
// Compile-time NK: K-loop fully unrolled (guards fold to constants).
// Bijective chunked XCD swizzle. M-tail loads unguarded, stores guarded.
// ---------------------------------------------------------------------------
template <int MODE, int NK>
__global__ __launch_bounds__(256) void gemm12864(
    const ushort_t* __restrict__ A, const ushort_t* __restrict__ Bt,
    ushort_t* __restrict__ Co, const float* __restrict__ bias,
    int M, int ldc)
{
    const int K = NK * 32;
    __shared__ __align__(16) ushort_t As[2][128][40];
    __shared__ __align__(16) ushort_t Bs[2][64][40];

    const int gx = gridDim.x;
    const int nwg = gx * gridDim.y;
    const int f = blockIdx.y * gx + blockIdx.x;
    const int q = nwg >> 3, rr_ = nwg & 7;
    const int xcd = f & 7, ii = f >> 3;
    const int swz = (xcd < rr_ ? xcd * (q + 1) : rr_ * (q + 1) + (xcd - rr_) * q) + ii;
    const int bx = swz % gx, by = swz / gx;

    const int tid = threadIdx.x;
    const int rowBase = by * 128;
    const int colBase = bx * 64;
    const int lr = tid >> 2, lk = (tid & 3) * 8;
    const int wv = tid >> 6, lane = tid & 63;
    const int wm = (wv >> 1) * 64, wn = (wv & 1) * 32;
    const int m16 = lane & 15, q4 = lane >> 4, kb = q4 * 8;

    const ushort_t* pa0 = A + (size_t)(rowBase + lr) * K + lk;
    const ushort_t* pa1 = pa0 + (size_t)64 * K;
    const ushort_t* pb  = Bt + (size_t)(colBase + lr) * K + lk;

    f32x4 acc[4][2];
#pragma unroll
    for (int i = 0; i < 4; i++)
#pragma unroll
        for (int j = 0; j < 2; j++) acc[i][j] = (f32x4){0.f, 0.f, 0.f, 0.f};

    uint4 Ua0, Ua1, Ub, Va0, Va1, Vb;
    auto gloadU = [&](int kt) {
        Ua0 = *(const uint4*)(pa0 + kt * 32);
        Ua1 = *(const uint4*)(pa1 + kt * 32);
        Ub  = *(const uint4*)(pb + kt * 32);
    };
    auto gloadV = [&](int kt) {
        Va0 = *(const uint4*)(pa0 + kt * 32);
        Va1 = *(const uint4*)(pa1 + kt * 32);
        Vb  = *(const uint4*)(pb + kt * 32);
    };
    auto swriteU = [&](int buf) {
        *(uint4*)&As[buf][lr][lk] = Ua0;
        *(uint4*)&As[buf][64 + lr][lk] = Ua1;
        *(uint4*)&Bs[buf][lr][lk] = Ub;
    };
    auto swriteV = [&](int buf) {
        *(uint4*)&As[buf][lr][lk] = Va0;
        *(uint4*)&As[buf][64 + lr][lk] = Va1;
        *(uint4*)&Bs[buf][lr][lk] = Vb;
    };
    auto compute = [&](int buf) {
        bf16x8 af[4];
#pragma unroll
        for (int mt = 0; mt < 4; mt++)
            af[mt] = *(const bf16x8*)&As[buf][wm + mt * 16 + m16][kb];
        bf16x8 b0 = *(const bf16x8*)&Bs[buf][wn + m16][kb];
        bf16x8 b1 = *(const bf16x8*)&Bs[buf][wn + 16 + m16][kb];
#pragma unroll
        for (int mt = 0; mt < 4; mt++) {
            acc[mt][0] = __builtin_amdgcn_mfma_f32_16x16x32_bf16(af[mt], b0, acc[mt][0], 0, 0, 0);
            acc[mt][1] = __builtin_amdgcn_mfma_f32_16x16x32_bf16(af[mt], b1, acc[mt][1], 0, 0, 0);
        }
    };

    gloadU(0);
    swriteU(0);
    gloadU(1);
    gloadV(2);
    __syncthreads();

#pragma unroll
    for (int kt = 0; kt < NK; kt += 2) {
        swriteU(1);
        if (kt + 3 < NK) gloadU(kt + 3);
        compute(0);
        __syncthreads();
        if (kt + 2 < NK) {
            swriteV(0);
            if (kt + 4 < NK) gloadV(kt + 4);
        }
        compute(1);
        __syncthreads();
    }

#pragma unroll
    for (int mt = 0; mt < 4; mt++)
#pragma unroll
        for (int nt = 0; nt < 2; nt++) {
            int col = colBase + wn + nt * 16 + m16;
#pragma unroll
            for (int r = 0; r < 4; r++) {
                int row = rowBase + wm + mt * 16 + q4 * 4 + r;
                if (row >= M) continue;
                float v = acc[mt][nt][r];
                if (MODE == M_QKV) {
                    Co[(size_t)row * ldc + col] = f2b(v);
                } else if (MODE == M_MLP1) {
                    float t = v + bias[col];
                    float u = t * (0.7978845608f + 0.0356774081f * t * t);
                    float e = __builtin_amdgcn_exp2f(2.885390082f * u);
                    float gl = t - t * __builtin_amdgcn_rcpf(e + 1.0f);
                    Co[(size_t)row * ldc + col] = f2b(gl);
                }
            }
        }
}

// ---------------------------------------------------------------------------
// 64x64-tile GEMM with BK=64 staging (OUT / MLP2), distance-2 pipelined.
// Doubling the staged K-depth halves the barrier/drain count (MLP2 24
// barrier-pairs instead of 48; OUT 6 instead of 12) -- the per-barrier
// vmcnt(0) drain is the structural stall of the 2-phase schedule (m233).
// LDS 36.9 KB -> 4 blocks/CU, but both grids are 870 blocks <= 4*256, so
// every block remains co-resident: zero occupancy cost for these shapes.
// NS = K/64 (compile-time, even). resid f32 += v + bias epilogue.
// ---------------------------------------------------------------------------
template <int MODE, int NS>
__global__ __launch_bounds__(256) void gemm64(
    const ushort_t* __restrict__ A, const ushort_t* __restrict__ Bt,
    float* __restrict__ resid, const float* __restrict__ bias,
    int M, int ldc)
{
    const int K = NS * 64;
    __shared__ __align__(16) ushort_t As[2][64][72];
    __shared__ __align__(16) ushort_t Bs[2][64][72];

    const int gx = gridDim.x, gy = gridDim.y;
    const int nwg = gx * gy;
    const int f = blockIdx.y * gx + blockIdx.x;
    const int q = nwg >> 3, rr_ = nwg & 7;
    const int xcd = f & 7, ii = f >> 3;
    const int swz = (xcd < rr_ ? xcd * (q + 1) : rr_ * (q + 1) + (xcd - rr_) * q) + ii;
    const int bx = swz % gx, by = swz / gx;

    const int tid = threadIdx.x;
    const int rowBase = by * 64;
    const int colBase = bx * 64;
    const int lr = tid >> 2, lk = (tid & 3) * 8;
    const int wv = tid >> 6, lane = tid & 63;
    const int wm = (wv >> 1) * 32, wn = (wv & 1) * 32;
    const int m16 = lane & 15, q4 = lane >> 4, kb = q4 * 8;

    const ushort_t* pa = A + (size_t)(rowBase + lr) * K + lk;
    const ushort_t* pb = Bt + (size_t)(colBase + lr) * K + lk;

    f32x4 acc[2][2];
#pragma unroll
    for (int i = 0; i < 2; i++)
#pragma unroll
        for (int j = 0; j < 2; j++) acc[i][j] = (f32x4){0.f, 0.f, 0.f, 0.f};

    uint4 Ua, Ua2, Ub, Ub2, Va, Va2, Vb, Vb2;
    auto gloadU = [&](int s) {
        int off = s * 64;
        Ua  = *(const uint4*)(pa + off);
        Ua2 = *(const uint4*)(pa + off + 32);
        Ub  = *(const uint4*)(pb + off);
        Ub2 = *(const uint4*)(pb + off + 32);
    };
    auto gloadV = [&](int s) {
        int off = s * 64;
        Va  = *(const uint4*)(pa + off);
        Va2 = *(const uint4*)(pa + off + 32);
        Vb  = *(const uint4*)(pb + off);
        Vb2 = *(const uint4*)(pb + off + 32);
    };
    auto swriteU = [&](int buf) {
        *(uint4*)&As[buf][lr][lk]      = Ua;
        *(uint4*)&As[buf][lr][lk + 32] = Ua2;
        *(uint4*)&Bs[buf][lr][lk]      = Ub;
        *(uint4*)&Bs[buf][lr][lk + 32] = Ub2;
    };
    auto swriteV = [&](int buf) {
        *(uint4*)&As[buf][lr][lk]      = Va;
        *(uint4*)&As[buf][lr][lk + 32] = Va2;
        *(uint4*)&Bs[buf][lr][lk]      = Vb;
        *(uint4*)&Bs[buf][lr][lk + 32] = Vb2;
    };
    auto compute = [&](int buf) {
#pragma unroll
        for (int h = 0; h < 2; h++) {
            int kc = h * 32 + kb;
            bf16x8 a0 = *(const bf16x8*)&As[buf][wm + m16][kc];
            bf16x8 a1 = *(const bf16x8*)&As[buf][wm + 16 + m16][kc];
            bf16x8 b0 = *(const bf16x8*)&Bs[buf][wn + m16][kc];
            bf16x8 b1 = *(const bf16x8*)&Bs[buf][wn + 16 + m16][kc];
            acc[0][0] = __builtin_amdgcn_mfma_f32_16x16x32_bf16(a0, b0, acc[0][0], 0, 0, 0);
            acc[0][1] = __builtin_amdgcn_mfma_f32_16x16x32_bf16(a0, b1, acc[0][1], 0, 0, 0);
            acc[1][0] = __builtin_amdgcn_mfma_f32_16x16x32_bf16(a1, b0, acc[1][0], 0, 0, 0);
            acc[1][1] = __builtin_amdgcn_mfma_f32_16x16x32_bf16(a1, b1, acc[1][1], 0, 0, 0);
        }
    };

    gloadU(0);
    swriteU(0);
    gloadU(1);
    gloadV(2);
    __syncthreads();

#pragma unroll
    for (int s = 0; s < NS; s += 2) {
        swriteU(1);
        if (s + 3 < NS) gloadU(s + 3);
        compute(0);
        __syncthreads();
        if (s + 2 < NS) {
            swriteV(0);
            if (s + 4 < NS) gloadV(s + 4);
        }
        compute(1);
        __syncthreads();
    }

#pragma unroll
    for (int im = 0; im < 2; im++)
#pragma unroll
        for (int in = 0; in < 2; in++) {
            int col = colBase + wn + in * 16 + m16;
#pragma unroll
            for (int r = 0; r < 4; r++) {
                int row = rowBase + wm + im * 16 + q4 * 4 + r;
                if (row >= M) continue;
                size_t o = (size_t)row * ldc + col;
                resid[o] = resid[o] + acc[im][in][r] + bias[col];
            }
        }
}

// ---------------------------------------------------------------------------
// Split-K (z=4) depth-2 double-buffered 64x64 GEMM for the SPT embed.
// Grid (6,48,4) = 1152 blocks, nk=30 per split. atomicAdd partials into
// resid (pre-initialized with spt_bias + pos). Chunked XCD swizzle.
// ---------------------------------------------------------------------------
__global__ __launch_bounds__(256) void gemm64_spt_split(
    const ushort_t* __restrict__ A, const ushort_t* __restrict__ Bt,
    float* __restrict__ resid, int rowOff)
{
    __shared__ __align__(16) ushort_t As[2][64][40];
    __shared__ __align__(16) ushort_t Bs[2][64][40];

    const int f = blockIdx.z * 288 + blockIdx.y * 6 + blockIdx.x;
    const int swz = (f & 7) * 144 + (f >> 3);
    const int bz = swz / 288;
    const int rem = swz - bz * 288;
    const int by = rem / 6, bx = rem - by * 6;

    const int K = 3840, nk = 30;
    const int rowBase = by * 64;
    const int colBase = bx * 64;
    const int kbase = bz * 960;

    const int tid = threadIdx.x;
    const int lr = tid >> 2, lk = (tid & 3) * 8;
    const int wv = tid >> 6, lane = tid & 63;
    const int wm = (wv >> 1) * 32, wn = (wv & 1) * 32;
    const int m16 = lane & 15, q4 = lane >> 4, kb = q4 * 8;

    const ushort_t* pa = A + (size_t)(rowBase + lr) * K + kbase + lk;
    const ushort_t* pb = Bt + (size_t)(colBase + lr) * K + kbase + lk;

    f32x4 acc[2][2];
#pragma unroll
    for (int i = 0; i < 2; i++)
#pragma unroll
        for (int j = 0; j < 2; j++) acc[i][j] = (f32x4){0.f, 0.f, 0.f, 0.f};

    uint4 Ua, Ub, Va, Vb;
    auto gloadU = [&](int kt) {
        Ua = *(const uint4*)(pa + kt * 32);
        Ub = *(const uint4*)(pb + kt * 32);
    };
    auto gloadV = [&](int kt) {
        Va = *(const uint4*)(pa + kt * 32);
        Vb = *(const uint4*)(pb + kt * 32);
    };
    auto swriteU = [&](int buf) {
        *(uint4*)&As[buf][lr][lk] = Ua;
        *(uint4*)&Bs[buf][lr][lk] = Ub;
    };
    auto swriteV = [&](int buf) {
        *(uint4*)&As[buf][lr][lk] = Va;
        *(uint4*)&Bs[buf][lr][lk] = Vb;
    };
    auto compute = [&](int buf) {
        bf16x8 a0 = *(const bf16x8*)&As[buf][wm + m16][kb];
        bf16x8 a1 = *(const bf16x8*)&As[buf][wm + 16 + m16][kb];
        bf16x8 b0 = *(const bf16x8*)&Bs[buf][wn + m16][kb];
        bf16x8 b1 = *(const bf16x8*)&Bs[buf][wn + 16 + m16][kb];
        acc[0][0] = __builtin_amdgcn_mfma_f32_16x16x32_bf16(a0, b0, acc[0][0], 0, 0, 0);
        acc[0][1] = __builtin_amdgcn_mfma_f32_16x16x32_bf16(a0, b1, acc[0][1], 0, 0, 0);
        acc[1][0] = __builtin_amdgcn_mfma_f32_16x16x32_bf16(a1, b0, acc[1][0], 0, 0, 0);
        acc[1][1] = __builtin_amdgcn_mfma_f32_16x16x32_bf16(a1, b1, acc[1][1], 0, 0, 0);
    };

    gloadU(0);
    swriteU(0);
    gloadU(1);
    gloadV(2);
    __syncthreads();

    for (int kt = 0; kt < nk; kt += 2) {
        swriteU(1);
        if (kt + 3 < nk) gloadU(kt + 3);
        compute(0);
        __syncthreads();
        if (kt + 2 < nk) {
            swriteV(0);
            if (kt + 4 < nk) gloadV(kt + 4);
        }
        compute(1);
        __syncthreads();
    }

#pragma unroll
    for (int im = 0; im < 2; im++)
#pragma unroll
        for (int in = 0; in < 2; in++) {
            int col = colBase + wn + in * 16 + m16;
#pragma unroll
            for (int r = 0; r < 4; r++) {
                int row = rowBase + wm + im * 16 + q4 * 4 + r;
                int grow = rowOff + row;
                int bb = grow / 576, p = grow - bb * 576;
                size_t o = ((size_t)(bb * SEQ_ + 1 + p)) * D_ + col;
                atomicAdd(&resid[o], acc[im][in][r]);
            }
        }
}

// ---------------------------------------------------------------------------
// Fused flash attention (one layer). Grid (10 qtiles, 96 b*h), 256 thr.
// Chunked XCD swizzle + one-iteration load-ahead + setprio on MFMA clusters.
// ---------------------------------------------------------------------------
__global__ __launch_bounds__(256) void attn_kernel(
    const ushort_t* __restrict__ qkv, ushort_t* __restrict__ attn,
    const float* __restrict__ temp, int layer)
{
    const int f = blockIdx.y * 10 + blockIdx.x;          // 960 blocks, 960%8==0
    const int swz = (f & 7) * 120 + (f >> 3);            // chunked XCD swizzle
    const int qt = swz % 10;
    const int bh = swz / 10;
    const int b = bh / 6, hd = bh - b * 6;
    const int tid = threadIdx.x;
    const int wv = tid >> 6, lane = tid & 63;
    const int m16 = lane & 15, q4 = lane >> 4;
    const float sc2 = expf(temp[layer]) * 1.44269504f;

    __shared__ __align__(16) ushort_t Ks[64][72];
    __shared__ __align__(16) ushort_t Vt[64][72];
    __shared__ __align__(16) ushort_t Pw[4][16][72];

    const int qrow = qt * 64 + wv * 16 + m16;
    const int qtok = qrow < SEQ_ ? qrow : SEQ_ - 1;
    const ushort_t* qb = qkv + ((size_t)(b * SEQ_ + qtok)) * 1152 + hd * 64;
    bf16x8 qf0 = *(const bf16x8*)(qb + q4 * 8);
    bf16x8 qf1 = *(const bf16x8*)(qb + 32 + q4 * 8);

    f32x4 accO[4];
#pragma unroll
    for (int dt = 0; dt < 4; dt++) accO[dt] = (f32x4){0.f, 0.f, 0.f, 0.f};
    float l_r[4] = {0.f, 0.f, 0.f, 0.f};

    const int skey = tid >> 2;
    const int scol = (tid & 3) * 16;
    const int vp   = tid & 31;
    const int vdh  = (tid >> 5) * 8;

    uint4 kv0, kv1, va, vb2;
    auto loadKV = [&](int kt) {
        int key = kt * 64 + skey;
        int gkey = key < SEQ_ ? key : 0;
        const ushort_t* kb_ = qkv + ((size_t)(b * SEQ_ + gkey)) * 1152 + 384 + hd * 64;
        kv0 = *(const uint4*)(kb_ + scol);
        kv1 = *(const uint4*)(kb_ + scol + 8);
        if (key >= SEQ_) { kv0 = (uint4){0, 0, 0, 0}; kv1 = kv0; }
        int vk0 = kt * 64 + 2 * vp;
        int t0 = vk0 < SEQ_ ? vk0 : 0;
        int t1 = vk0 + 1 < SEQ_ ? vk0 + 1 : 0;
        va  = *(const uint4*)(qkv + ((size_t)(b * SEQ_ + t0)) * 1152 + 768 + hd * 64 + vdh);
        vb2 = *(const uint4*)(qkv + ((size_t)(b * SEQ_ + t1)) * 1152 + 768 + hd * 64 + vdh);
        if (vk0 >= SEQ_) va = (uint4){0, 0, 0, 0};
        if (vk0 + 1 >= SEQ_) vb2 = (uint4){0, 0, 0, 0};
    };

    loadKV(0);

    for (int kt = 0; kt < 10; kt++) {
        __syncthreads();
        *(uint4*)&Ks[skey][scol] = kv0;
        *(uint4*)&Ks[skey][scol + 8] = kv1;
        {
            const ushort_t* e0 = (const ushort_t*)&va;
            const ushort_t* e1 = (const ushort_t*)&vb2;
#pragma unroll
            for (int j = 0; j < 8; j++) {
                unsigned int pack = (unsigned int)e0[j] | ((unsigned int)e1[j] << 16);
                *(unsigned int*)&Vt[vdh + j][2 * vp] = pack;
            }
        }
        __syncthreads();
        if (kt + 1 < 10) loadKV(kt + 1);   // overlaps with compute below

        f32x4 s[4];
        __builtin_amdgcn_s_setprio(1);
#pragma unroll
        for (int ct = 0; ct < 4; ct++) {
            bf16x8 b0 = *(const bf16x8*)&Ks[ct * 16 + m16][q4 * 8];
            bf16x8 b1 = *(const bf16x8*)&Ks[ct * 16 + m16][32 + q4 * 8];
            f32x4 z = (f32x4){0.f, 0.f, 0.f, 0.f};
            z = __builtin_amdgcn_mfma_f32_16x16x32_bf16(qf0, b0, z, 0, 0, 0);
            z = __builtin_amdgcn_mfma_f32_16x16x32_bf16(qf1, b1, z, 0, 0, 0);
            s[ct] = z;
        }
        __builtin_amdgcn_s_setprio(0);
        const int rowb = qt * 64 + wv * 16 + q4 * 4;
#pragma unroll
        for (int r = 0; r < 4; r++) {
            float rs = 0.f;
#pragma unroll
            for (int ct = 0; ct < 4; ct++) {
                int col = kt * 64 + ct * 16 + m16;
                float v = s[ct][r] * sc2;
                if (col >= SEQ_ || col == rowb + r) v = -1.0e30f;
                float p = __builtin_amdgcn_exp2f(v);
                s[ct][r] = p;
                rs += p;
            }
            rs += __shfl_xor(rs, 1);
            rs += __shfl_xor(rs, 2);
            rs += __shfl_xor(rs, 4);
            rs += __shfl_xor(rs, 8);
            l_r[r] += rs;
        }
#pragma unroll
        for (int ct = 0; ct < 4; ct++)
#pragma unroll
            for (int r = 0; r < 4; r++)
                Pw[wv][q4 * 4 + r][ct * 16 + m16] = f2b(s[ct][r]);
        bf16x8 pf0 = *(const bf16x8*)&Pw[wv][m16][q4 * 8];
        bf16x8 pf1 = *(const bf16x8*)&Pw[wv][m16][32 + q4 * 8];
        __builtin_amdgcn_s_setprio(1);
#pragma unroll
        for (int dt = 0; dt < 4; dt++) {
            bf16x8 vb0 = *(const bf16x8*)&Vt[dt * 16 + m16][q4 * 8];
            bf16x8 vb1 = *(const bf16x8*)&Vt[dt * 16 + m16][32 + q4 * 8];
            f32x4 o = accO[dt];
            o = __builtin_amdgcn_mfma_f32_16x16x32_bf16(pf0, vb0, o, 0, 0, 0);
            o = __builtin_amdgcn_mfma_f32_16x16x32_bf16(pf1, vb1, o, 0, 0, 0);
            accO[dt] = o;
        }
        __builtin_amdgcn_s_setprio(0);
    }

    const int rowb = qt * 64 + wv * 16 + q4 * 4;
#pragma unroll
    for (int r = 0; r < 4; r++) {
        int grow = rowb + r;
        if (grow >= SEQ_) continue;
        float inv = 1.f / l_r[r];
        ushort_t* op = attn + ((size_t)(b * SEQ_ + grow)) * 384 + hd * 64;
#pragma unroll
        for (int dt = 0; dt < 4; dt++)
            op[dt * 16 + m16] = f2b(accO[dt][r] * inv);
    }
}

// ---------------------------------------------------------------------------
// SPT shift-gather + LayerNorm, plane-major (coalesced). One block = 1 patch.
// ---------------------------------------------------------------------------
__global__ __launch_bounds__(256) void spt_ln_kernel(
    const float* __restrict__ img, const float* __restrict__ gg,
    const float* __restrict__ bb_, ushort_t* __restrict__ Xn, int r0)
{
    int bp = r0 + blockIdx.x;
    int b = bp / 576, p = bp - b * 576;
    int ph = p / 24, pw = p - ph * 24;

    __shared__ float vals[3840];
    __shared__ float red[10];

    const int tid = threadIdx.x;
    const int p1 = tid >> 4, p2 = tid & 15;

    float s = 0.f, sq = 0.f;
#pragma unroll
    for (int plane = 0; plane < 15; plane++) {
        int g5 = plane / 3, ch = plane - g5 * 3;
        int row = ph * 16 + p1, col = pw * 16 + p2;
        if (g5 == 1) col -= 1;
        else if (g5 == 2) col += 1;
        else if (g5 == 3) row -= 1;
        else if (g5 == 4) row += 1;
        float v = 0.f;
        if (row >= 0 && row < 384 && col >= 0 && col < 384)
            v = img[((size_t)(b * 3 + ch) * 384 + row) * 384 + col];
        vals[tid * 15 + plane] = v;
        s += v; sq += v * v;
    }
#pragma unroll
    for (int off = 32; off > 0; off >>= 1) {
        s += __shfl_xor(s, off);
        sq += __shfl_xor(sq, off);
    }
    int wid = tid >> 6;
    if ((tid & 63) == 0) { red[wid] = s; red[4 + wid] = sq; }
    __syncthreads();
    if (tid == 0) {
        float S = red[0] + red[1] + red[2] + red[3];
        float Q = red[4] + red[5] + red[6] + red[7];
        float mean = S / 3840.f;
        float var = Q / 3840.f - mean * mean;
        red[8] = mean;
        red[9] = rsqrtf(var + 1e-5f);
    }
    __syncthreads();
    float mean = red[8], rstd = red[9];
#pragma unroll
    for (int i = 0; i < 15; i++) {
        int k = tid + i * 256;
        float v = (vals[k] - mean) * rstd * gg[k] + bb_[k];
        Xn[(size_t)blockIdx.x * 3840 + k] = f2b(v);
    }
}

// ---------------------------------------------------------------------------
// Per-token LayerNorm: 4 rows/block (1 wave each). Full-lane layout:
// each lane owns float4 @ 4*lane + float2 @ 256+2*lane (no divergent
// half-wave tranche; all loads/stores coalesced).
// ---------------------------------------------------------------------------
__global__ __launch_bounds__(256) void ln_kernel(
    const float* __restrict__ x, const float* __restrict__ g,
    const float* __restrict__ b, ushort_t* __restrict__ h)
{
    int row = blockIdx.x * 4 + (threadIdx.x >> 6);
    int lane = threadIdx.x & 63;
    const float* xr = x + (size_t)row * 384;
    float4 a = *(const float4*)(xr + lane * 4);
    float2 c = *(const float2*)(xr + 256 + lane * 2);
    float s = a.x + a.y + a.z + a.w + c.x + c.y;
    float sq = a.x * a.x + a.y * a.y + a.z * a.z + a.w * a.w
             + c.x * c.x + c.y * c.y;
#pragma unroll
    for (int off = 32; off > 0; off >>= 1) {
        s += __shfl_xor(s, off);
        sq += __shfl_xor(sq, off);
    }
    float mean = s / 384.f;
    float var = sq / 384.f - mean * mean;
    float rstd = rsqrtf(var + 1e-5f);
    float4 gv = *(const float4*)(g + lane * 4);
    float2 gc = *(const float2*)(g + 256 + lane * 2);
    float4 bv = *(const float4*)(b + lane * 4);
    float2 bc = *(const float2*)(b + 256 + lane * 2);
    ushort_t* hr = h + (size_t)row * 384;
    {
        unsigned int lo = (unsigned int)f2b((a.x - mean) * rstd * gv.x + bv.x)
                        | ((unsigned int)f2b((a.y - mean) * rstd * gv.y + bv.y) << 16);
        unsigned int hi = (unsigned int)f2b((a.z - mean) * rstd * gv.z + bv.z)
                        | ((unsigned int)f2b((a.w - mean) * rstd * gv.w + bv.w) << 16);
        *(uint2*)&hr[lane * 4] = make_uint2(lo, hi);
    }
    {
        unsigned int w = (unsigned int)f2b((c.x - mean) * rstd * gc.x + bc.x)
                       | ((unsigned int)f2b((c.y - mean) * rstd * gc.y + bc.y) << 16);
        *(unsigned int*)&hr[256 + lane * 2] = w;
    }
}

// ---------------------------------------------------------------------------
// Init residual: x[b,0,:] = cls + pos[0]; x[b,1+p,:] = spt_bias + pos[1+p].
// ---------------------------------------------------------------------------
__global__ void init_x_kernel(const float* __restrict__ cls,
                              const float* __restrict__ pos,
                              const float* __restrict__ spt_bias,
                              float* __restrict__ x)
{
    int s = blockIdx.x, b = blockIdx.y, d = threadIdx.x;
    float base = (s == 0) ? cls[d] : spt_bias[d];
    x[((size_t)b * SEQ_ + s) * D_ + d] = base + pos[(size_t)s * D_ + d];
}

// ---------------------------------------------------------------------------
extern "C" void kernel_launch(void* const* d_in, const int* in_sizes, int n_in,
                              void* d_out, int out_size, void* d_ws, size_t ws_size,
                              hipStream_t stream)
{
    const float* img      = (const float*)d_in[0];
    const float* spt_g    = (const float*)d_in[1];
    const float* spt_b    = (const float*)d_in[2];
    const float* spt_w    = (const float*)d_in[3];
    const float* spt_bias = (const float*)d_in[4];
    const float* pos      = (const float*)d_in[5];
    const float* clsp     = (const float*)d_in[6];
    const float* attn_g   = (const float*)d_in[7];
    const float* attn_b   = (const float*)d_in[8];
    const float* temp     = (const float*)d_in[9];
    const float* wqkv     = (const float*)d_in[10];
    const float* wout     = (const float*)d_in[11];
    const float* bout     = (const float*)d_in[12];
    const float* ff_g     = (const float*)d_in[13];
    const float* ff_b     = (const float*)d_in[14];
    const float* w1       = (const float*)d_in[15];
    const float* b1       = (const float*)d_in[16];
    const float* w2       = (const float*)d_in[17];
    const float* b2       = (const float*)d_in[18];

    float* x = (float*)d_out;   // residual f32 lives in d_out

    // ---- workspace layout ----
    char* base = (char*)d_ws;
    ushort_t* qkv   = (ushort_t*)base;
    ushort_t* attn  = (ushort_t*)(base + (size_t)NTOK * 1152 * 2);
    ushort_t* Xn    = (ushort_t*)base;
    ushort_t* gbuf  = (ushort_t*)base;
    ushort_t* spt_wt = (ushort_t*)(base + 23592960);
    char* p2 = base + (size_t)NTOK * 1536 * 2;         // 28,360,704
    ushort_t* h  = (ushort_t*)p2;
    char* p3 = p2 + (size_t)NTOK * 384 * 2;            // + 7,090,176
    ushort_t* W6 = (ushort_t*)p3;                      // + 21,233,664

    prep_all_kernel<<<2952, 256, 0, stream>>>(wqkv, wout, w1, w2, spt_w, W6, spt_wt);
    init_x_kernel<<<dim3(SEQ_, 16), 384, 0, stream>>>(clsp, pos, spt_bias, x);

    for (int c = 0; c < 3; c++) {
        int r0 = c * 3072;
        spt_ln_kernel<<<3072, 256, 0, stream>>>(img, spt_g, spt_b, Xn, r0);
        gemm64_spt_split<<<dim3(6, 48, 4), 256, 0, stream>>>(Xn, spt_wt, x, r0);
    }

    for (int l = 0; l < 6; l++) {
        ushort_t* qkv_t  = W6 + (size_t)l * 1769472;
        ushort_t* wout_t = qkv_t + 442368;
        ushort_t* w1_t   = wout_t + 147456;
        ushort_t* w2_t   = w1_t + 589824;
        ln_kernel<<<NTOK / 4, 256, 0, stream>>>(x, attn_g + l * 384, attn_b + l * 384, h);
        gemm12864<M_QKV, 12><<<dim3(18, 73), 256, 0, stream>>>(
            h, qkv_t, qkv, nullptr, NTOK, 1152);
        attn_kernel<<<dim3(10, 96), 256, 0, stream>>>(qkv, attn, temp, l);
        gemm64<M_OUT, 6><<<dim3(6, 145), 256, 0, stream>>>(
            attn, wout_t, x, bout + l * 384, NTOK, 384);
        ln_kernel<<<NTOK / 4, 256, 0, stream>>>(x, ff_g + l * 384, ff_b + l * 384, h);
        gemm12864<M_MLP1, 12><<<dim3(24, 73), 256, 0, stream>>>(
            h, w1_t, gbuf, b1 + l * 1536, NTOK, 1536);
        gemm64<M_MLP2, 24><<<dim3(6, 145), 256, 0, stream>>>(
            gbuf, w2_t, x, b2 + l * 384, NTOK, 384);
    }
}